// Round 1
// 1072.326 us; speedup vs baseline: 1.2739x; 1.2739x over previous
//
#include <hip/hip_runtime.h>
#include <math.h>

#define IMG   160
#define HWSZ  25600
#define NB    4
#define CIN   256
#define COUT1 384
#define BIGK  90000

// output offsets (in floats)
#define OFF_LMAP 0
#define OFF_JMAP 102400
#define OFF_JOFF 204800
#define OFF_CMAP 409600
#define OFF_COFF 512000
#define OFF_LVEC 716800
#define OFF_LOI  1126400
#define OFF_MASK 1206400

// workspace offsets (bytes)
static const size_t WS_Y1    = 0;
static const size_t WS_JSORT = (size_t)NB * COUT1 * HWSZ * 4;            // 157286400
static const size_t WS_CSORT = WS_JSORT + (size_t)NB * 32768 * 8;
static const size_t WS_JUNC  = WS_CSORT + (size_t)NB * 32768 * 8;
static const size_t WS_JVAL  = WS_JUNC + (size_t)NB * 300 * 2 * 4;
static const size_t WS_LKEY  = WS_JVAL + (size_t)NB * 300 * 4;
static const size_t WS_WPK   = WS_LKEY + (size_t)NB * 8192 * 4;
// Wpack: 12 octiles * 8 icc * 9 taps * 32 ocl * 64 shorts * 2 B = 3,538,944
static const size_t WS_FPK         = WS_WPK + (size_t)12 * 8 * 9 * 32 * 64 * 2;
static const size_t WS_NEED_LEGACY = WS_FPK;                              // ~163 MB
// packed feat: [b][icc 8][py 162][px 162][128 B]  (zero border, slot-swizzled)
static const size_t WS_NEED_PK     = WS_FPK + (size_t)NB * 8 * 162 * 162 * 128;  // ~258 MB

typedef unsigned long long u64;
typedef __attribute__((ext_vector_type(8))) short short8;
typedef __attribute__((ext_vector_type(4))) float f32x4;
typedef __attribute__((ext_vector_type(4))) int int4v;

union frag_u { short8 s8; u64 u[2]; int4v v; };

__device__ __forceinline__ float clip_coord(float v) {
    return fminf(fmaxf(v, 0.0f), 159.9999f);
}
__device__ __forceinline__ float sigmoidf(float v) {
    return 1.0f / (1.0f + expf(-v));
}
__device__ __forceinline__ unsigned short f2bf(float f) {   // RNE
    unsigned u = __float_as_uint(f);
    return (unsigned short)((u + 0x7FFFu + ((u >> 16) & 1u)) >> 16);
}
__device__ __forceinline__ float bf2f(unsigned short h) {
    return __uint_as_float((unsigned)h << 16);
}

// async 16B global -> LDS (DMA). LDS dest must be wave-uniform base; HW adds lane*16.
__device__ __forceinline__ void async_copy16(void* lds, const void* g) {
    __builtin_amdgcn_global_load_lds(
        (const __attribute__((address_space(1))) unsigned int*)g,
        (__attribute__((address_space(3))) unsigned int*)lds, 16, 0, 0);
}

// ===========================================================================
// ============================  NEW (pk) PATH  ==============================
// ===========================================================================

// ---------------------------------------------------------------------------
// Pre-pack w1 for the DMA+b128 conv1:
//   Wpack[octile 12][icc 8][tap 9][ocl 32][8 phys 16B-slots][8 shorts]
//   physical 16B slot p16 holds LOGICAL slot p16 ^ (ocl & 7);
//   logical slot l16 = t*4+quad -> term t, channels quad*8..quad*8+7 (k-order)
// ---------------------------------------------------------------------------
__global__ void wpack_pk_kernel(const float* __restrict__ w1, short* __restrict__ wpk) {
    int e = blockIdx.x * 256 + threadIdx.x;      // 12*8*9*32*64 = 1,769,472 exact
    int row = e >> 6, sp = e & 63;
    int ocl = row & 31;
    int tap = (row >> 5) % 9;
    int icc = (row / 288) & 7;
    int octile = row / 2304;
    int p16 = sp >> 3, j = sp & 7;
    int l16 = p16 ^ (ocl & 7);                   // logical 16B slot
    int ql = l16 * 8 + j;                        // logical short index 0..63
    int term = ql >> 5, icl = ql & 31;
    int oc = octile * 32 + ocl, ic = icc * 32 + icl;
    float a = w1[((size_t)oc * CIN + ic) * 9 + tap];
    unsigned short hi = f2bf(a);
    wpk[e] = (term == 0) ? (short)hi : (short)f2bf(a - bf2f(hi));
}

// ---------------------------------------------------------------------------
// Pre-pack feat into split-bf16, zero-bordered, slot-swizzled global image:
//   fpk[b][icc][py 0..161][px 0..161][128 B]
//   physical 16B slot p holds logical slot p ^ s, s = (2*py+px)&7.
//   logical slot l: term t=l>>2, channels (l&3)*8 .. +7 of group icc (k-order).
// Same f2bf/bf2f math as the legacy in-kernel conversion -> bitwise identical.
// ---------------------------------------------------------------------------
__global__ __launch_bounds__(256) void pack_feat_kernel(
    const float* __restrict__ feat, short* __restrict__ fpk) {
    int e = blockIdx.x * 256 + threadIdx.x;      // 4*8*162*162*8 = 6,718,464 exact
    int p = e & 7;
    int rest = e >> 3;                           // (b*8+icc)*26244 + py*162 + px
    int px = rest % 162;
    int t2 = rest / 162;
    int py = t2 % 162;
    int bi = t2 / 162;                           // b*8 + icc
    int s = (2 * py + px) & 7;
    int l = p ^ s;                               // logical slot stored here
    int term = l >> 2;
    int c0 = (l & 3) * 8;
    int gy = py - 1, gx = px - 1;
    bool valid = ((unsigned)gy < (unsigned)IMG) && ((unsigned)gx < (unsigned)IMG);
    const float* fs = feat + (size_t)(bi * 32 + c0) * HWSZ + (valid ? gy * IMG + gx : 0);
    unsigned d[4];
#pragma unroll
    for (int j2 = 0; j2 < 4; ++j2) {
        float va = valid ? fs[(size_t)(2 * j2) * HWSZ]     : 0.0f;
        float vb = valid ? fs[(size_t)(2 * j2 + 1) * HWSZ] : 0.0f;
        unsigned short ha = f2bf(va), hb = f2bf(vb);
        unsigned short oa = term ? f2bf(va - bf2f(ha)) : ha;
        unsigned short ob = term ? f2bf(vb - bf2f(hb)) : hb;
        d[j2] = (unsigned)oa | ((unsigned)ob << 16);
    }
    int4v o = { (int)d[0], (int)d[1], (int)d[2], (int)d[3] };
    *(int4v*)(fpk + (size_t)rest * 64 + p * 8) = o;   // byte addr e*16, coalesced
}

// ---------------------------------------------------------------------------
// conv1 via MFMA implicit GEMM, 2-term bf16 split (4 products), DMA staging.
// A and B staged with global_load_lds (linear LDS), fragments read as single
// conflict-free XOR-swizzled ds_read_b128.  MFMA order identical to legacy.
// ---------------------------------------------------------------------------
__global__ __launch_bounds__(256, 2) void conv1_mfma_pk(
    const short* __restrict__ fpk, const short* __restrict__ wpk,
    const float* __restrict__ b1, const float* __restrict__ gamma,
    const float* __restrict__ beta, const float* __restrict__ mean,
    const float* __restrict__ var, float* __restrict__ y1) {
    const int bid   = blockIdx.x;                 // 0..4799
    const int slot  = bid >> 3;                   // 0..599
    const int tile  = (bid & 7) + ((slot / 12) << 3);   // XCD-local tile set
    const int octile = slot - (slot / 12) * 12;   // 0..11
    const int bb = tile / 100, tt = tile % 100;
    const int ty = (tt / 10) * 16, tx = (tt % 10) * 16;
    const int oc0 = octile * 32;
    const int tid  = threadIdx.x;
    const int w    = tid >> 6;              // wave: px rows w*4..w*4+3
    const int lane = tid & 63;
    const int quad = lane >> 4;
    const int l15  = lane & 15;
    const int wbase = tid & 192;            // w*64, wave-uniform

    __shared__ __align__(16) short Alds[288 * 64];   // 36864 B, linear copy of wpk block
    __shared__ __align__(16) short Blds[324 * 64];   // 41472 B, [pos][128B phys-swizzled]

    // A-frag byte offset within Alds row block for term t (single b128 each):
    //   row (mi*16+l15): phys slot = (t*4+quad) ^ (l15&7)  -> 2 lanes/bank (free)
    int aoff[2];
#pragma unroll
    for (int t = 0; t < 2; ++t)
        aoff[t] = l15 * 128 + ((((t << 2) | quad) ^ (l15 & 7)) << 4);

    f32x4 acc[2][4];
#pragma unroll
    for (int mi = 0; mi < 2; ++mi)
#pragma unroll
        for (int nj = 0; nj < 4; ++nj) acc[mi][nj] = (f32x4){0.f, 0.f, 0.f, 0.f};

    const char* asrc0 = (const char*)wpk + (size_t)(octile * 8) * 36864;

#pragma unroll 1
    for (int icc = 0; icc < 8; ++icc) {
        __syncthreads();                    // prev iter's frag reads complete
        // ---- A DMA: 2304 x 16B chunks, exact 9 per thread, linear
        {
            const char* asrc = asrc0 + (size_t)icc * 36864;
#pragma unroll
            for (int i = 0; i < 9; ++i) {
                int k = i * 256 + tid;
                async_copy16((char*)Alds + (size_t)(i * 256 + wbase) * 16,
                             asrc + (size_t)k * 16);
            }
        }
        // ---- B DMA: 2592 x 16B chunks (18 rows x 144), 10 full + 32 rem
        {
            const char* bsrc = (const char*)fpk
                + (((size_t)(bb * 8 + icc) * 162 + ty) * 162 + tx) * 128;
#pragma unroll
            for (int it = 0; it < 10; ++it) {
                int k = it * 256 + tid;
                int hy = (int)((unsigned)k / 144u);
                int r  = k - hy * 144;
                async_copy16((char*)Blds + (size_t)(it * 256 + wbase) * 16,
                             bsrc + (size_t)hy * (162 * 128) + (size_t)r * 16);
            }
            if (tid < 32) {                 // chunks 2560..2591: hy=17, r=112..143
                const int4v vv = *(const int4v*)(bsrc + (size_t)17 * (162 * 128)
                                                 + (size_t)(112 + tid) * 16);
                *(int4v*)((char*)Blds + (size_t)(2560 + tid) * 16) = vv;
            }
        }
        __syncthreads();                    // compiler drains vmcnt/lgkmcnt here

#pragma unroll
        for (int tap = 0; tap < 9; ++tap) {
            const int sy = tap / 3, sx = tap % 3;
            frag_u Af[2][2], Bf[2][4];
#pragma unroll
            for (int t = 0; t < 2; ++t) {
#pragma unroll
                for (int mi = 0; mi < 2; ++mi) {
                    const char* ap = (const char*)Alds
                        + (size_t)(tap * 32 + mi * 16) * 128 + aoff[t];
                    Af[t][mi].v = *(const int4v*)ap;
                }
#pragma unroll
                for (int nj = 0; nj < 4; ++nj) {
                    int pos = (w * 4 + nj + sy) * 18 + (l15 + sx);
                    const char* bp = (const char*)Blds + (size_t)pos * 128
                        + ((((t << 2) | quad) ^ (pos & 7)) << 4);
                    Bf[t][nj].v = *(const int4v*)bp;
                }
            }
#pragma unroll
            for (int mi = 0; mi < 2; ++mi)
#pragma unroll
                for (int nj = 0; nj < 4; ++nj) {
                    acc[mi][nj] = __builtin_amdgcn_mfma_f32_16x16x32_bf16(
                        Af[0][mi].s8, Bf[0][nj].s8, acc[mi][nj], 0, 0, 0);
                    acc[mi][nj] = __builtin_amdgcn_mfma_f32_16x16x32_bf16(
                        Af[0][mi].s8, Bf[1][nj].s8, acc[mi][nj], 0, 0, 0);
                    acc[mi][nj] = __builtin_amdgcn_mfma_f32_16x16x32_bf16(
                        Af[1][mi].s8, Bf[0][nj].s8, acc[mi][nj], 0, 0, 0);
                    acc[mi][nj] = __builtin_amdgcn_mfma_f32_16x16x32_bf16(
                        Af[1][mi].s8, Bf[1][nj].s8, acc[mi][nj], 0, 0, 0);
                }
        }
    }

    // ---- epilogue: BN + ReLU.  C/D: col(l15)=px col, row(quad*4+r)=oc.
#pragma unroll
    for (int nj = 0; nj < 4; ++nj) {
        const int gy = ty + w * 4 + nj, gx = tx + l15;
#pragma unroll
        for (int mi = 0; mi < 2; ++mi)
#pragma unroll
            for (int r = 0; r < 4; ++r) {
                const int oc = oc0 + mi * 16 + quad * 4 + r;
                float v = acc[mi][nj][r] + b1[oc];
                v = (v - mean[oc]) * (gamma[oc] / sqrtf(var[oc] + 1e-5f)) + beta[oc];
                y1[((size_t)(bb * COUT1 + oc)) * HWSZ + gy * IMG + gx] = fmaxf(v, 0.0f);
            }
    }
}

// ===========================================================================
// =======================  LEGACY PATH (ws fallback)  =======================
// ===========================================================================

__global__ void wpack_kernel(const float* __restrict__ w1, short* __restrict__ wpk) {
    int e = blockIdx.x * 256 + threadIdx.x;      // 12*8*9*32*64 = 1,769,472 exact
    int row = e >> 6, sp = e & 63;
    int ocl = row & 31;
    int tap = (row >> 5) % 9;
    int icc = (row / 288) & 7;
    int octile = row / 2304;
    int s = (sp >> 2) ^ (ocl & 15);              // logical slot
    int ql = s * 4 + (sp & 3);                   // logical short index 0..63
    int term = ql >> 5, icl = ql & 31;
    int oc = octile * 32 + ocl, ic = icc * 32 + icl;
    float a = w1[((size_t)oc * CIN + ic) * 9 + tap];
    unsigned short hi = f2bf(a);
    wpk[e] = (term == 0) ? (short)hi : (short)f2bf(a - bf2f(hi));
}

__global__ __launch_bounds__(256, 2) void conv1_mfma(
    const float* __restrict__ feat, const short* __restrict__ wpk,
    const float* __restrict__ b1, const float* __restrict__ gamma,
    const float* __restrict__ beta, const float* __restrict__ mean,
    const float* __restrict__ var, float* __restrict__ y1) {
    const int bid   = blockIdx.x;                 // 0..4799
    const int slot  = bid >> 3;                   // 0..599
    const int tile  = (bid & 7) + ((slot / 12) << 3);   // XCD-local tile set
    const int octile = slot - (slot / 12) * 12;   // 0..11
    const int bb = tile / 100, tt = tile % 100;
    const int ty = (tt / 10) * 16, tx = (tt % 10) * 16;
    const int oc0 = octile * 32;
    const int tid  = threadIdx.x;
    const int w    = tid >> 6;              // wave: px rows w*4..w*4+3
    const int lane = tid & 63;
    const int quad = lane >> 4;
    const int l15  = lane & 15;

    __shared__ short Alds[288 * 64];        // [tap*32+ocl][64 sh, perm'd] 36864 B
    __shared__ short Blds[324 * 68];        // [hy*18+hx][t0 32|t1 32|pad] 44064 B

    int aoff[2][2];
#pragma unroll
    for (int t = 0; t < 2; ++t)
#pragma unroll
        for (int h = 0; h < 2; ++h)
            aoff[t][h] = l15 * 128 + (((t * 8 + quad * 2 + h) ^ l15) * 8);

    f32x4 acc[2][4];
#pragma unroll
    for (int mi = 0; mi < 2; ++mi)
#pragma unroll
        for (int nj = 0; nj < 4; ++nj) acc[mi][nj] = (f32x4){0.f, 0.f, 0.f, 0.f};

    const int4v* asrc_base = (const int4v*)wpk + (size_t)(octile * 8) * 2304;
    unsigned* Bd = (unsigned*)Blds;

    // B prefetch registers: 21 iters x 2 floats
    float pv0[21], pv1[21];

    // ---- prefetch chunk 0
#pragma unroll
    for (int ii = 0; ii < 21; ++ii) {
        int i = tid + ii * 256;
        if (i < 5184) {
            int icp = i / 324, hp = i - icp * 324;
            int hy = hp / 18, hx = hp - hy * 18;
            int gy = ty + hy - 1, gx = tx + hx - 1;
            bool valid = ((unsigned)gy < IMG) && ((unsigned)gx < IMG);
            const float* fs = feat + ((size_t)(bb * CIN + icp * 2)) * HWSZ
                                   + (valid ? (gy * IMG + gx) : 0);
            pv0[ii] = valid ? fs[0]    : 0.0f;
            pv1[ii] = valid ? fs[HWSZ] : 0.0f;
        }
    }

#pragma unroll 1
    for (int icc = 0; icc < 8; ++icc) {
        __syncthreads();                    // prev chunk's frag reads complete
        // ---- stage A: 36864 B = 2304 int4 (wpk is L2-hot)
        {
            const int4v* asrc = asrc_base + (size_t)icc * 2304;
            int4v* adst = (int4v*)Alds;
#pragma unroll
            for (int i = 0; i < 9; ++i)
                adst[tid + i * 256] = asrc[tid + i * 256];
        }
        // ---- write prefetched B: convert + split to LDS
#pragma unroll
        for (int ii = 0; ii < 21; ++ii) {
            int i = tid + ii * 256;
            if (i < 5184) {
                int icp = i / 324, hp = i - icp * 324;
                float v0 = pv0[ii], v1 = pv1[ii];
                unsigned short h0 = f2bf(v0), h1 = f2bf(v1);
                unsigned short m0 = f2bf(v0 - bf2f(h0)), m1 = f2bf(v1 - bf2f(h1));
                Bd[hp * 34 + icp]      = (unsigned)h0 | ((unsigned)h1 << 16);
                Bd[hp * 34 + 16 + icp] = (unsigned)m0 | ((unsigned)m1 << 16);
            }
        }
        __syncthreads();

        // ---- issue next chunk's B loads (overlap with compute below)
        if (icc < 7) {
#pragma unroll
            for (int ii = 0; ii < 21; ++ii) {
                int i = tid + ii * 256;
                if (i < 5184) {
                    int icp = i / 324, hp = i - icp * 324;
                    int hy = hp / 18, hx = hp - hy * 18;
                    int gy = ty + hy - 1, gx = tx + hx - 1;
                    bool valid = ((unsigned)gy < IMG) && ((unsigned)gx < IMG);
                    const float* fs = feat
                        + ((size_t)(bb * CIN + (icc + 1) * 32 + icp * 2)) * HWSZ
                        + (valid ? (gy * IMG + gx) : 0);
                    pv0[ii] = valid ? fs[0]    : 0.0f;
                    pv1[ii] = valid ? fs[HWSZ] : 0.0f;
                }
            }
        }

#pragma unroll
        for (int tap = 0; tap < 9; ++tap) {
            const int sy = tap / 3, sx = tap % 3;
            frag_u Af[2][2], Bf[2][4];
#pragma unroll
            for (int t = 0; t < 2; ++t) {
#pragma unroll
                for (int mi = 0; mi < 2; ++mi) {
                    const char* base = (const char*)Alds + (tap * 32 + mi * 16) * 128;
                    Af[t][mi].u[0] = *(const u64*)(base + aoff[t][0]);
                    Af[t][mi].u[1] = *(const u64*)(base + aoff[t][1]);
                }
#pragma unroll
                for (int nj = 0; nj < 4; ++nj) {
                    int pos = (w * 4 + nj + sy) * 18 + (l15 + sx);
                    const short* bp = &Blds[pos * 68 + t * 32 + quad * 8];
                    Bf[t][nj].u[0] = *(const u64*)bp;
                    Bf[t][nj].u[1] = *(const u64*)(bp + 4);
                }
            }
#pragma unroll
            for (int mi = 0; mi < 2; ++mi)
#pragma unroll
                for (int nj = 0; nj < 4; ++nj) {
                    acc[mi][nj] = __builtin_amdgcn_mfma_f32_16x16x32_bf16(
                        Af[0][mi].s8, Bf[0][nj].s8, acc[mi][nj], 0, 0, 0);
                    acc[mi][nj] = __builtin_amdgcn_mfma_f32_16x16x32_bf16(
                        Af[0][mi].s8, Bf[1][nj].s8, acc[mi][nj], 0, 0, 0);
                    acc[mi][nj] = __builtin_amdgcn_mfma_f32_16x16x32_bf16(
                        Af[1][mi].s8, Bf[0][nj].s8, acc[mi][nj], 0, 0, 0);
                    acc[mi][nj] = __builtin_amdgcn_mfma_f32_16x16x32_bf16(
                        Af[1][mi].s8, Bf[1][nj].s8, acc[mi][nj], 0, 0, 0);
                }
        }
    }

    // ---- epilogue: BN + ReLU.  C/D: col(l15)=px col, row(quad*4+r)=oc.
#pragma unroll
    for (int nj = 0; nj < 4; ++nj) {
        const int gy = ty + w * 4 + nj, gx = tx + l15;
#pragma unroll
        for (int mi = 0; mi < 2; ++mi)
#pragma unroll
            for (int r = 0; r < 4; ++r) {
                const int oc = oc0 + mi * 16 + quad * 4 + r;
                float v = acc[mi][nj][r] + b1[oc];
                v = (v - mean[oc]) * (gamma[oc] / sqrtf(var[oc] + 1e-5f)) + beta[oc];
                y1[((size_t)(bb * COUT1 + oc)) * HWSZ + gy * IMG + gx] = fmaxf(v, 0.0f);
            }
    }
}

// ===========================================================================
// ===========================  SHARED TAIL  =================================
// ===========================================================================

// ---------------------------------------------------------------------------
// conv2: grouped 3x3, only the SEL channels; sigmoid where needed; -> d_out.
// ---------------------------------------------------------------------------
__global__ __launch_bounds__(256, 2) void conv2_kernel(
    const float* __restrict__ y1, const float* __restrict__ w2,
    const float* __restrict__ b2, float* __restrict__ out) {
    const int KH[6]   = {1, 1, 2, 1, 2, 4};
    const int REG[6]  = {OFF_LMAP, OFF_JMAP, OFF_JOFF, OFF_CMAP, OFF_COFF, OFF_LVEC};
    const int SIGF[6] = {1, 1, 0, 1, 0, 0};

    const int bz = blockIdx.z;
    const int b  = bz / 6;
    const int h  = bz % 6;
    const int k  = KH[h];
    const int tx = blockIdx.x * 16, ty = blockIdx.y * 16;
    const int lx = threadIdx.x, ly = threadIdx.y;
    const int tid = ly * 16 + lx;

    __shared__ float tin[16][18][33];
    float acc[4] = {0.0f, 0.0f, 0.0f, 0.0f};

    const float* yb = y1 + ((size_t)(b * COUT1 + h * 64)) * HWSZ;

    for (int ic0 = 0; ic0 < 64; ic0 += 16) {
        __syncthreads();
        for (int i = tid; i < 5184; i += 256) {
            int c = i / 324, rem = i - c * 324;
            int r = rem / 18, col = rem - r * 18;
            int gy = ty - 1 + r, gx = tx - 1 + col;
            float v = 0.0f;
            if (gy >= 0 && gy < IMG && gx >= 0 && gx < IMG)
                v = yb[(size_t)(ic0 + c) * HWSZ + gy * IMG + gx];
            tin[c][r][col] = v;
        }
        __syncthreads();
#pragma unroll 4
        for (int c = 0; c < 16; ++c) {
            float n0 = tin[c][ly][lx],     n1 = tin[c][ly][lx + 1],     n2 = tin[c][ly][lx + 2];
            float n3 = tin[c][ly + 1][lx], n4 = tin[c][ly + 1][lx + 1], n5 = tin[c][ly + 1][lx + 2];
            float n6 = tin[c][ly + 2][lx], n7 = tin[c][ly + 2][lx + 1], n8 = tin[c][ly + 2][lx + 2];
#pragma unroll
            for (int o = 0; o < 4; ++o) {
                if (o < k) {
                    const float* wp = w2 + ((size_t)((h * 4 + o) * 64 + (ic0 + c))) * 9;
                    acc[o] = fmaf(n0, wp[0], fmaf(n1, wp[1], fmaf(n2, wp[2],
                             fmaf(n3, wp[3], fmaf(n4, wp[4], fmaf(n5, wp[5],
                             fmaf(n6, wp[6], fmaf(n7, wp[7], fmaf(n8, wp[8], acc[o])))))))));
                }
            }
        }
    }

    const int p = (ty + ly) * IMG + tx + lx;
    for (int o = 0; o < k; ++o) {
        float v = acc[o] + b2[h * 4 + o];
        if (SIGF[h]) v = sigmoidf(v);
        out[REG[h] + ((size_t)(b * k + o)) * HWSZ + p] = v;
    }
}

// ---------------------------------------------------------------------------
// NMS on jmap + pack sort keys (value_bits<<32 | ~index  == lax.top_k order).
// ---------------------------------------------------------------------------
__global__ void nms_pack_kernel(const float* __restrict__ out,
                                u64* __restrict__ jsort,
                                u64* __restrict__ csort) {
    const int g = blockIdx.x;           // 0..399
    const int b = g / 100, q = g % 100;
    const int p = q * 256 + threadIdx.x;
    const float* jm = out + OFF_JMAP + (size_t)b * HWSZ;
    const float* cm = out + OFF_CMAP + (size_t)b * HWSZ;

    const int x = p % IMG, y = p / IMG;
    float v = jm[p];
    float mx = v;
#pragma unroll
    for (int dy = -1; dy <= 1; ++dy)
#pragma unroll
        for (int dx = -1; dx <= 1; ++dx) {
            int nx = x + dx, ny = y + dy;
            if (nx >= 0 && nx < IMG && ny >= 0 && ny < IMG)
                mx = fmaxf(mx, jm[ny * IMG + nx]);
        }
    float nmsv = (v == mx) ? v : 0.0f;

    u64 tagj = ((u64)__float_as_uint(nmsv) << 32)
             | (u64)(0xFFFFFFFFu - (unsigned)p);
    u64 tagc = ((u64)__float_as_uint(cm[p]) << 32)
             | (u64)(0xFFFFFFFFu - (unsigned)p);
    jsort[(size_t)b * 32768 + p] = tagj;
    csort[(size_t)b * 32768 + p] = tagc;
    if (q < 28) {                        // pad 25600..32767 with minimal keys
        int pp = 25600 + q * 256 + threadIdx.x;
        jsort[(size_t)b * 32768 + pp] = 0ull;
        csort[(size_t)b * 32768 + pp] = 0ull;
    }
}

// ---------------------------------------------------------------------------
// Hybrid bitonic sort, descending, 8 arrays x 32768 u64.
// ---------------------------------------------------------------------------
__global__ __launch_bounds__(1024) void sort64_ldsA(u64* __restrict__ buf) {
    __shared__ u64 s[8192];
    const size_t base = (size_t)blockIdx.x * 8192;   // 32 chunks (8 arrays x 4)
    const int cbase = (blockIdx.x & 3) * 8192;       // chunk offset within array
    for (int i = threadIdx.x; i < 8192; i += 1024) s[i] = buf[base + i];
    for (int k = 2; k <= 8192; k <<= 1)
        for (int j = k >> 1; j > 0; j >>= 1) {
            __syncthreads();
            for (int t = threadIdx.x; t < 4096; t += 1024) {
                int i = ((t & ~(j - 1)) << 1) | (t & (j - 1));
                int l = i | j;
                bool desc = (((i + cbase) & k) == 0);
                u64 x = s[i], y = s[l];
                if (desc ? (x < y) : (x > y)) { s[i] = y; s[l] = x; }
            }
        }
    __syncthreads();
    for (int i = threadIdx.x; i < 8192; i += 1024) buf[base + i] = s[i];
}

__global__ void sort64_gstep(u64* __restrict__ buf, int k, int j) {
    int t = blockIdx.x * 256 + threadIdx.x;          // 8 arrays * 16384 pairs
    int arr = t >> 14, p = t & 16383;
    int i = ((p & ~(j - 1)) << 1) | (p & (j - 1));
    int l = i | j;
    bool desc = ((i & k) == 0);
    u64* a = buf + (size_t)arr * 32768;
    u64 x = a[i], y = a[l];
    if (desc ? (x < y) : (x > y)) { a[i] = y; a[l] = x; }
}

__global__ __launch_bounds__(1024) void sort64_ldsB(u64* __restrict__ buf, int k) {
    __shared__ u64 s[8192];
    const size_t base = (size_t)blockIdx.x * 8192;
    const int cbase = (blockIdx.x & 3) * 8192;
    for (int i = threadIdx.x; i < 8192; i += 1024) s[i] = buf[base + i];
    for (int j = 4096; j > 0; j >>= 1) {
        __syncthreads();
        for (int t = threadIdx.x; t < 4096; t += 1024) {
            int i = ((t & ~(j - 1)) << 1) | (t & (j - 1));
            int l = i | j;
            bool desc = (((i + cbase) & k) == 0);
            u64 x = s[i], y = s[l];
            if (desc ? (x < y) : (x > y)) { s[i] = y; s[l] = x; }
        }
    }
    __syncthreads();
    for (int i = threadIdx.x; i < 8192; i += 1024) buf[base + i] = s[i];
}

// Full-LDS bitonic sort, ascending, 8192 int keys (one array per block).
__global__ __launch_bounds__(1024) void sort32_lds(int* __restrict__ buf) {
    __shared__ int s[8192];
    int* a = buf + (size_t)blockIdx.x * 8192;
    for (int i = threadIdx.x; i < 8192; i += 1024) s[i] = a[i];
    for (int k = 2; k <= 8192; k <<= 1)
        for (int j = k >> 1; j > 0; j >>= 1) {
            __syncthreads();
            for (int t = threadIdx.x; t < 4096; t += 1024) {
                int i = ((t & ~(j - 1)) << 1) | (t & (j - 1));
                int l = i | j;
                bool asc = ((i & k) == 0);
                int x = s[i], y = s[l];
                if (asc ? (x > y) : (x < y)) { s[i] = y; s[l] = x; }
            }
        }
    __syncthreads();
    for (int i = threadIdx.x; i < 8192; i += 1024) a[i] = s[i];
}

// Top-300 junctions: coordinates + validity.
__global__ void junction_kernel(const u64* __restrict__ jsort,
                                const float* __restrict__ out,
                                float* __restrict__ junc, int* __restrict__ jvalid) {
    const int b = blockIdx.x;
    const int t = threadIdx.x;
    if (t >= 300) return;
    u64 key = jsort[(size_t)b * 32768 + t];
    float score  = __uint_as_float((unsigned)(key >> 32));
    unsigned idx = 0xFFFFFFFFu - (unsigned)(key & 0xFFFFFFFFull);
    const float* j0 = out + OFF_JOFF + (size_t)(b * 2) * HWSZ;
    const float* j1 = j0 + HWSZ;
    float jx = (float)(idx % IMG) + j0[idx] + 0.5f;
    float jy = (float)(idx / IMG) + j1[idx] + 0.5f;
    junc[(size_t)(b * 300 + t) * 2]     = clip_coord(jx);
    junc[(size_t)(b * 300 + t) * 2 + 1] = clip_coord(jy);
    jvalid[b * 300 + t] = (score >= 0.008f) ? 1 : 0;
}

// Top-5000 centers -> line endpoints -> nearest-junction keys.
__global__ void lines_kernel(const u64* __restrict__ csort,
                             const float* __restrict__ junc,
                             const int* __restrict__ jvalid,
                             const float* __restrict__ out,
                             int* __restrict__ lkeys) {
    const int b = blockIdx.y;
    const int t = blockIdx.x * 256 + threadIdx.x;

    __shared__ float jx[300], jy[300];
    __shared__ int jv[300];
    for (int i = threadIdx.x; i < 300; i += 256) {
        jx[i] = junc[(size_t)(b * 300 + i) * 2];
        jy[i] = junc[(size_t)(b * 300 + i) * 2 + 1];
        jv[i] = jvalid[b * 300 + i];
    }
    __syncthreads();

    if (t >= 8192) return;
    if (t >= 5000) { lkeys[b * 8192 + t] = 0x7FFFFFFF; return; }

    u64 key = csort[(size_t)b * 32768 + t];
    unsigned idx = 0xFFFFFFFFu - (unsigned)(key & 0xFFFFFFFFull);
    const float* c0 = out + OFF_COFF + (size_t)(b * 2) * HWSZ;
    const float* c1 = c0 + HWSZ;
    const float* lv = out + OFF_LVEC + (size_t)(b * 4) * HWSZ;

    float cx = (float)(idx % IMG) + c0[idx] + 0.5f;
    float cy = (float)(idx / IMG) + c1[idx] + 0.5f;
    float e0x = clip_coord(cx + lv[idx]);
    float e0y = clip_coord(cy + lv[HWSZ + idx]);
    float e1x = clip_coord(cx + lv[2 * HWSZ + idx]);
    float e1y = clip_coord(cy + lv[3 * HWSZ + idx]);

    float m1 = 1e18f, m2 = 1e18f;
    int i1 = 0, i2 = 0;
    for (int j = 0; j < 300; ++j) {
        if (jv[j]) {
            float dx = e0x - jx[j], dy = e0y - jy[j];
            float d = dx * dx + dy * dy;
            if (d < m1) { m1 = d; i1 = j; }
            dx = e1x - jx[j]; dy = e1y - jy[j];
            d = dx * dx + dy * dy;
            if (d < m2) { m2 = d; i2 = j; }
        }
    }
    int imin = min(i1, i2), imax = max(i1, i2);
    lkeys[b * 8192 + t] = (i1 != i2) ? (imin * 300 + imax) : BIGK;
}

// Dedup sorted keys -> line segments + mask.
__global__ void finalize_kernel(const int* __restrict__ lkeys,
                                const float* __restrict__ junc,
                                float* __restrict__ out) {
    const int b = blockIdx.y;
    const int t = blockIdx.x * 256 + threadIdx.x;
    if (t >= 5000) return;
    const int* lk = lkeys + b * 8192;
    int sk = lk[t];
    bool first = ((t == 0) || (sk != lk[t - 1])) && (sk < BIGK);
    int a  = first ? sk / 300 : 0;
    int bb = first ? sk % 300 : 0;
    float p0x = junc[(size_t)(b * 300 + a) * 2];
    float p0y = junc[(size_t)(b * 300 + a) * 2 + 1];
    float p1x = junc[(size_t)(b * 300 + bb) * 2];
    float p1y = junc[(size_t)(b * 300 + bb) * 2 + 1];
    if (p0y > p1y) {
        float tx = p0x; p0x = p1x; p1x = tx;
        float ty = p0y; p0y = p1y; p1y = ty;
    }
    size_t base = OFF_LOI + (size_t)(b * 5000 + t) * 4;
    out[base]     = p0x;
    out[base + 1] = p0y;
    out[base + 2] = p1x;
    out[base + 3] = p1y;
    out[OFF_MASK + b * 5000 + t] = first ? 1.0f : 0.0f;
}

extern "C" void kernel_launch(void* const* d_in, const int* in_sizes, int n_in,
                              void* d_out, int out_size, void* d_ws, size_t ws_size,
                              hipStream_t stream) {
    const float* feat  = (const float*)d_in[0];
    const float* w1    = (const float*)d_in[1];
    const float* b1    = (const float*)d_in[2];
    const float* gamma = (const float*)d_in[3];
    const float* beta  = (const float*)d_in[4];
    const float* mean  = (const float*)d_in[5];
    const float* var   = (const float*)d_in[6];
    const float* w2    = (const float*)d_in[7];
    const float* b2    = (const float*)d_in[8];
    float* out = (float*)d_out;
    char*  ws  = (char*)d_ws;

    if (ws_size < WS_NEED_LEGACY) return;

    float* y1 = (float*)(ws + WS_Y1);
    u64* jsort = (u64*)(ws + WS_JSORT);
    float* junc = (float*)(ws + WS_JUNC);
    int* jvalid = (int*)(ws + WS_JVAL);
    int* lkeys  = (int*)(ws + WS_LKEY);
    u64* csort = (u64*)(ws + WS_CSORT);
    short* wpk = (short*)(ws + WS_WPK);
    short* fpk = (short*)(ws + WS_FPK);

    if (ws_size >= WS_NEED_PK) {
        // 0a. pack conv1 weights (16B-slot swizzle) -> wpk
        wpack_pk_kernel<<<dim3(6912), dim3(256), 0, stream>>>(w1, wpk);
        // 0b. pack feat into split-bf16 zero-bordered swizzled image -> fpk
        pack_feat_kernel<<<dim3(26244), dim3(256), 0, stream>>>(feat, fpk);
        // 1. conv1 + BN + ReLU via DMA-staged MFMA
        conv1_mfma_pk<<<dim3(4800), dim3(256), 0, stream>>>(
            fpk, wpk, b1, gamma, beta, mean, var, y1);
    } else {
        // fallback: legacy path (workspace too small for fpk)
        wpack_kernel<<<dim3(6912), dim3(256), 0, stream>>>(w1, wpk);
        conv1_mfma<<<dim3(4800), dim3(256), 0, stream>>>(
            feat, wpk, b1, gamma, beta, mean, var, y1);
    }

    // 2. conv2 (grouped, SEL channels only) -> maps in d_out
    conv2_kernel<<<dim3(10, 10, NB * 6), dim3(16, 16), 0, stream>>>(y1, w2, b2, out);

    // 3. NMS + pack sort keys
    nms_pack_kernel<<<dim3(NB * 100), dim3(256), 0, stream>>>(out, jsort, csort);

    // 4. hybrid bitonic sort of 8 u64 arrays (4 jmap + 4 cmap, contiguous)
    sort64_ldsA<<<dim3(32), dim3(1024), 0, stream>>>(jsort);
    sort64_gstep<<<dim3(512), dim3(256), 0, stream>>>(jsort, 16384, 8192);
    sort64_ldsB<<<dim3(32), dim3(1024), 0, stream>>>(jsort, 16384);
    sort64_gstep<<<dim3(512), dim3(256), 0, stream>>>(jsort, 32768, 16384);
    sort64_gstep<<<dim3(512), dim3(256), 0, stream>>>(jsort, 32768, 8192);
    sort64_ldsB<<<dim3(32), dim3(1024), 0, stream>>>(jsort, 32768);

    // 5. junctions
    junction_kernel<<<dim3(NB), dim3(320), 0, stream>>>(jsort, out, junc, jvalid);

    // 6. line keys
    lines_kernel<<<dim3(32, NB), dim3(256), 0, stream>>>(csort, junc, jvalid, out, lkeys);

    // 7. sort line keys ascending (full LDS)
    sort32_lds<<<dim3(NB), dim3(1024), 0, stream>>>(lkeys);

    // 8. dedup + emit loi/mask
    finalize_kernel<<<dim3(20, NB), dim3(256), 0, stream>>>(lkeys, junc, out);
}

// Round 2
// 967.890 us; speedup vs baseline: 1.4114x; 1.1079x over previous
//
#include <hip/hip_runtime.h>
#include <math.h>

#define IMG   160
#define HWSZ  25600
#define NB    4
#define CIN   256
#define COUT1 384
#define BIGK  90000

// output offsets (in floats)
#define OFF_LMAP 0
#define OFF_JMAP 102400
#define OFF_JOFF 204800
#define OFF_CMAP 409600
#define OFF_COFF 512000
#define OFF_LVEC 716800
#define OFF_LOI  1126400
#define OFF_MASK 1206400

// workspace offsets (bytes)
static const size_t WS_Y1    = 0;
static const size_t WS_JSORT = (size_t)NB * COUT1 * HWSZ * 4;            // 157286400
static const size_t WS_CSORT = WS_JSORT + (size_t)NB * 32768 * 8;
static const size_t WS_JUNC  = WS_CSORT + (size_t)NB * 32768 * 8;
static const size_t WS_JVAL  = WS_JUNC + (size_t)NB * 300 * 2 * 4;
static const size_t WS_LKEY  = WS_JVAL + (size_t)NB * 300 * 4;
static const size_t WS_WPK   = WS_LKEY + (size_t)NB * 8192 * 4;
// Wpack: 12 octiles * 8 icc * 9 taps * 32 ocl * 64 shorts * 2 B = 3,538,944
static const size_t WS_NEED_LEGACY = WS_WPK + (size_t)12 * 8 * 9 * 32 * 64 * 2;
static const size_t WS_BNS   = WS_NEED_LEGACY;                           // 384 f32
static const size_t WS_FPK   = WS_BNS + 384 * 4;
// packed feat: [b][icc 8][py 162][px 162][128 B]  (zero border, slot-swizzled)
static const size_t WS_NEED_PK = WS_FPK + (size_t)NB * 8 * 162 * 162 * 128;  // ~258 MB

typedef unsigned long long u64;
typedef __attribute__((ext_vector_type(8))) short short8;
typedef __attribute__((ext_vector_type(4))) float f32x4;
typedef __attribute__((ext_vector_type(4))) int int4v;

union frag_u { short8 s8; u64 u[2]; int4v v; };

__device__ __forceinline__ float clip_coord(float v) {
    return fminf(fmaxf(v, 0.0f), 159.9999f);
}
__device__ __forceinline__ float sigmoidf(float v) {
    return 1.0f / (1.0f + expf(-v));
}
__device__ __forceinline__ unsigned short f2bf(float f) {   // RNE
    unsigned u = __float_as_uint(f);
    return (unsigned short)((u + 0x7FFFu + ((u >> 16) & 1u)) >> 16);
}
__device__ __forceinline__ float bf2f(unsigned short h) {
    return __uint_as_float((unsigned)h << 16);
}

// async 16B global -> LDS (DMA). LDS dest must be wave-uniform base; HW adds lane*16.
__device__ __forceinline__ void async_copy16(void* lds, const void* g) {
    __builtin_amdgcn_global_load_lds(
        (const __attribute__((address_space(1))) unsigned int*)g,
        (__attribute__((address_space(3))) unsigned int*)lds, 16, 0, 0);
}

// ===========================================================================
// ============================  NEW (pk) PATH  ==============================
// ===========================================================================

// BN scale precompute: bns[oc] = gamma[oc]/sqrtf(var[oc]+eps) (bitwise same
// expression as the old in-epilogue computation).
__global__ void bnscale_kernel(const float* __restrict__ gamma,
                               const float* __restrict__ var,
                               float* __restrict__ bns) {
    int i = blockIdx.x * 256 + threadIdx.x;
    if (i < COUT1) bns[i] = gamma[i] / sqrtf(var[i] + 1e-5f);
}

// ---------------------------------------------------------------------------
// Pre-pack w1 for the DMA+b128 conv1:
//   Wpack[octile 12][icc 8][tap 9][ocl 32][8 phys 16B-slots][8 shorts]
//   physical 16B slot p16 holds LOGICAL slot p16 ^ (ocl & 7);
//   logical slot l16 = t*4+quad -> term t, channels quad*8..quad*8+7 (k-order)
// ---------------------------------------------------------------------------
__global__ void wpack_pk_kernel(const float* __restrict__ w1, short* __restrict__ wpk) {
    int e = blockIdx.x * 256 + threadIdx.x;      // 12*8*9*32*64 = 1,769,472 exact
    int row = e >> 6, sp = e & 63;
    int ocl = row & 31;
    int tap = (row >> 5) % 9;
    int icc = (row / 288) & 7;
    int octile = row / 2304;
    int p16 = sp >> 3, j = sp & 7;
    int l16 = p16 ^ (ocl & 7);                   // logical 16B slot
    int ql = l16 * 8 + j;                        // logical short index 0..63
    int term = ql >> 5, icl = ql & 31;
    int oc = octile * 32 + ocl, ic = icc * 32 + icl;
    float a = w1[((size_t)oc * CIN + ic) * 9 + tap];
    unsigned short hi = f2bf(a);
    wpk[e] = (term == 0) ? (short)hi : (short)f2bf(a - bf2f(hi));
}

// ---------------------------------------------------------------------------
// Pre-pack feat into split-bf16, zero-bordered, slot-swizzled global image:
//   fpk[b][icc][py 0..161][px 0..161][128 B]
//   physical 16B slot p holds logical slot p ^ s, s = (2*py+px)&7.
//   logical slot l: term t=l>>2, channels (l&3)*8 .. +7 of group icc (k-order).
// v2: thread owns a LOGICAL slot pair (c4, c4+4) -> reads each feat value
// once (both terms from one read) and reads are 16-px-contiguous full lines.
// Bytes written are identical to v1.
// ---------------------------------------------------------------------------
__global__ __launch_bounds__(256) void pack_feat_kernel(
    const float* __restrict__ feat, short* __restrict__ fpk) {
    const int tid = threadIdx.x;
    const int c4  = (tid >> 4) & 3;                       // channel quarter 0..3
    const int r0  = (tid & 15) | (((tid >> 6) & 3) << 4); // 0..63
    const int rest = blockIdx.x * 64 + r0;   // (b*8+icc)*26244 + py*162 + px
    const int px = rest % 162;
    const int t2 = rest / 162;
    const int py = t2 % 162;
    const int bi = t2 / 162;                 // b*8 + icc
    const int s  = (2 * py + px) & 7;
    const int gy = py - 1, gx = px - 1;
    const bool valid = ((unsigned)gy < (unsigned)IMG) && ((unsigned)gx < (unsigned)IMG);
    const float* fs = feat + (size_t)(bi * 32 + c4 * 8) * HWSZ
                           + (valid ? gy * IMG + gx : 0);
    unsigned hi4[4], lo4[4];
#pragma unroll
    for (int j2 = 0; j2 < 4; ++j2) {
        float va = valid ? fs[(size_t)(2 * j2) * HWSZ]     : 0.0f;
        float vb = valid ? fs[(size_t)(2 * j2 + 1) * HWSZ] : 0.0f;
        unsigned short ha = f2bf(va), hb = f2bf(vb);
        unsigned short la = f2bf(va - bf2f(ha)), lb = f2bf(vb - bf2f(hb));
        hi4[j2] = (unsigned)ha | ((unsigned)hb << 16);
        lo4[j2] = (unsigned)la | ((unsigned)lb << 16);
    }
    const int p0 = c4 ^ s;            // physical slot holding logical l=c4 (term0)
    const int p1 = (c4 | 4) ^ s;      // physical slot holding logical l=c4+4 (term1)
    int4v* base = (int4v*)(fpk + (size_t)rest * 64);
    base[p0] = (int4v){ (int)hi4[0], (int)hi4[1], (int)hi4[2], (int)hi4[3] };
    base[p1] = (int4v){ (int)lo4[0], (int)lo4[1], (int)lo4[2], (int)lo4[3] };
}

// ---------------------------------------------------------------------------
// conv1 via MFMA implicit GEMM, 3-product bf16 split (hi*hi + hi*lo + lo*hi;
// the lo*lo term is ~2^-18 relative and dropped).  DMA staging, conflict-free
// swizzled ds_read_b128.  sx-outer tap loop reuses 6 B-row fragments across
// the 3 sy taps (72 instead of 108 LDS reads per icc).
// ---------------------------------------------------------------------------
__global__ __launch_bounds__(256, 2) void conv1_mfma_pk(
    const short* __restrict__ fpk, const short* __restrict__ wpk,
    const float* __restrict__ b1, const float* __restrict__ bns,
    const float* __restrict__ beta, const float* __restrict__ mean,
    float* __restrict__ y1) {
    const int bid   = blockIdx.x;                 // 0..4799
    const int slot  = bid >> 3;                   // 0..599
    const int tile  = (bid & 7) + ((slot / 12) << 3);   // XCD-local tile set
    const int octile = slot - (slot / 12) * 12;   // 0..11
    const int bb = tile / 100, tt = tile % 100;
    const int ty = (tt / 10) * 16, tx = (tt % 10) * 16;
    const int oc0 = octile * 32;
    const int tid  = threadIdx.x;
    const int w    = tid >> 6;              // wave: px rows w*4..w*4+3
    const int lane = tid & 63;
    const int quad = lane >> 4;
    const int l15  = lane & 15;
    const int wbase = tid & 192;            // w*64, wave-uniform

    __shared__ __align__(16) short Alds[288 * 64];   // 36864 B, linear copy of wpk block
    __shared__ __align__(16) short Blds[324 * 64];   // 41472 B, [pos][128B phys-swizzled]

    // A-frag byte offset within Alds row block for term t (single b128 each):
    //   row (mi*16+l15): phys slot = (t*4+quad) ^ (l15&7)  -> 2 lanes/bank (free)
    int aoff[2];
#pragma unroll
    for (int t = 0; t < 2; ++t)
        aoff[t] = l15 * 128 + ((((t << 2) | quad) ^ (l15 & 7)) << 4);

    f32x4 acc[2][4];
#pragma unroll
    for (int mi = 0; mi < 2; ++mi)
#pragma unroll
        for (int nj = 0; nj < 4; ++nj) acc[mi][nj] = (f32x4){0.f, 0.f, 0.f, 0.f};

    const char* asrc0 = (const char*)wpk + (size_t)(octile * 8) * 36864;

#pragma unroll 1
    for (int icc = 0; icc < 8; ++icc) {
        __syncthreads();                    // prev iter's frag reads complete
        // ---- A DMA: 2304 x 16B chunks, exact 9 per thread, linear
        {
            const char* asrc = asrc0 + (size_t)icc * 36864;
#pragma unroll
            for (int i = 0; i < 9; ++i) {
                int k = i * 256 + tid;
                async_copy16((char*)Alds + (size_t)(i * 256 + wbase) * 16,
                             asrc + (size_t)k * 16);
            }
        }
        // ---- B DMA: 2592 x 16B chunks (18 rows x 144), 10 full + 32 rem
        {
            const char* bsrc = (const char*)fpk
                + (((size_t)(bb * 8 + icc) * 162 + ty) * 162 + tx) * 128;
#pragma unroll
            for (int it = 0; it < 10; ++it) {
                int k = it * 256 + tid;
                int hy = (int)((unsigned)k / 144u);
                int r  = k - hy * 144;
                async_copy16((char*)Blds + (size_t)(it * 256 + wbase) * 16,
                             bsrc + (size_t)hy * (162 * 128) + (size_t)r * 16);
            }
            if (tid < 32) {                 // chunks 2560..2591: hy=17, r=112..143
                const int4v vv = *(const int4v*)(bsrc + (size_t)17 * (162 * 128)
                                                 + (size_t)(112 + tid) * 16);
                *(int4v*)((char*)Blds + (size_t)(2560 + tid) * 16) = vv;
            }
        }
        __syncthreads();                    // compiler drains vmcnt/lgkmcnt here

#pragma unroll
        for (int sx = 0; sx < 3; ++sx) {
            frag_u Bf[2][6];                // rows w*4 .. w*4+5, this sx column
#pragma unroll
            for (int t = 0; t < 2; ++t)
#pragma unroll
                for (int rr = 0; rr < 6; ++rr) {
                    int pos = (w * 4 + rr) * 18 + (l15 + sx);
                    const char* bp = (const char*)Blds + (size_t)pos * 128
                        + ((((t << 2) | quad) ^ (pos & 7)) << 4);
                    Bf[t][rr].v = *(const int4v*)bp;
                }
#pragma unroll
            for (int sy = 0; sy < 3; ++sy) {
                const int tap = sy * 3 + sx;
                frag_u Af[2][2];
#pragma unroll
                for (int t = 0; t < 2; ++t)
#pragma unroll
                    for (int mi = 0; mi < 2; ++mi) {
                        const char* ap = (const char*)Alds
                            + (size_t)(tap * 32 + mi * 16) * 128 + aoff[t];
                        Af[t][mi].v = *(const int4v*)ap;
                    }
#pragma unroll
                for (int mi = 0; mi < 2; ++mi)
#pragma unroll
                    for (int nj = 0; nj < 4; ++nj) {
                        acc[mi][nj] = __builtin_amdgcn_mfma_f32_16x16x32_bf16(
                            Af[0][mi].s8, Bf[0][nj + sy].s8, acc[mi][nj], 0, 0, 0);
                        acc[mi][nj] = __builtin_amdgcn_mfma_f32_16x16x32_bf16(
                            Af[0][mi].s8, Bf[1][nj + sy].s8, acc[mi][nj], 0, 0, 0);
                        acc[mi][nj] = __builtin_amdgcn_mfma_f32_16x16x32_bf16(
                            Af[1][mi].s8, Bf[0][nj + sy].s8, acc[mi][nj], 0, 0, 0);
                    }
            }
        }
    }

    // ---- epilogue: BN + ReLU.  C/D: col(l15)=px col, row(quad*4+r)=oc.
#pragma unroll
    for (int nj = 0; nj < 4; ++nj) {
        const int gy = ty + w * 4 + nj, gx = tx + l15;
#pragma unroll
        for (int mi = 0; mi < 2; ++mi)
#pragma unroll
            for (int r = 0; r < 4; ++r) {
                const int oc = oc0 + mi * 16 + quad * 4 + r;
                float v = acc[mi][nj][r] + b1[oc];
                v = (v - mean[oc]) * bns[oc] + beta[oc];
                y1[((size_t)(bb * COUT1 + oc)) * HWSZ + gy * IMG + gx] = fmaxf(v, 0.0f);
            }
    }
}

// ===========================================================================
// =======================  LEGACY PATH (ws fallback)  =======================
// ===========================================================================

__global__ void wpack_kernel(const float* __restrict__ w1, short* __restrict__ wpk) {
    int e = blockIdx.x * 256 + threadIdx.x;      // 12*8*9*32*64 = 1,769,472 exact
    int row = e >> 6, sp = e & 63;
    int ocl = row & 31;
    int tap = (row >> 5) % 9;
    int icc = (row / 288) & 7;
    int octile = row / 2304;
    int s = (sp >> 2) ^ (ocl & 15);              // logical slot
    int ql = s * 4 + (sp & 3);                   // logical short index 0..63
    int term = ql >> 5, icl = ql & 31;
    int oc = octile * 32 + ocl, ic = icc * 32 + icl;
    float a = w1[((size_t)oc * CIN + ic) * 9 + tap];
    unsigned short hi = f2bf(a);
    wpk[e] = (term == 0) ? (short)hi : (short)f2bf(a - bf2f(hi));
}

__global__ __launch_bounds__(256, 2) void conv1_mfma(
    const float* __restrict__ feat, const short* __restrict__ wpk,
    const float* __restrict__ b1, const float* __restrict__ gamma,
    const float* __restrict__ beta, const float* __restrict__ mean,
    const float* __restrict__ var, float* __restrict__ y1) {
    const int bid   = blockIdx.x;                 // 0..4799
    const int slot  = bid >> 3;                   // 0..599
    const int tile  = (bid & 7) + ((slot / 12) << 3);   // XCD-local tile set
    const int octile = slot - (slot / 12) * 12;   // 0..11
    const int bb = tile / 100, tt = tile % 100;
    const int ty = (tt / 10) * 16, tx = (tt % 10) * 16;
    const int oc0 = octile * 32;
    const int tid  = threadIdx.x;
    const int w    = tid >> 6;              // wave: px rows w*4..w*4+3
    const int lane = tid & 63;
    const int quad = lane >> 4;
    const int l15  = lane & 15;

    __shared__ short Alds[288 * 64];        // [tap*32+ocl][64 sh, perm'd] 36864 B
    __shared__ short Blds[324 * 68];        // [hy*18+hx][t0 32|t1 32|pad] 44064 B

    int aoff[2][2];
#pragma unroll
    for (int t = 0; t < 2; ++t)
#pragma unroll
        for (int h = 0; h < 2; ++h)
            aoff[t][h] = l15 * 128 + (((t * 8 + quad * 2 + h) ^ l15) * 8);

    f32x4 acc[2][4];
#pragma unroll
    for (int mi = 0; mi < 2; ++mi)
#pragma unroll
        for (int nj = 0; nj < 4; ++nj) acc[mi][nj] = (f32x4){0.f, 0.f, 0.f, 0.f};

    const int4v* asrc_base = (const int4v*)wpk + (size_t)(octile * 8) * 2304;
    unsigned* Bd = (unsigned*)Blds;

    // B prefetch registers: 21 iters x 2 floats
    float pv0[21], pv1[21];

    // ---- prefetch chunk 0
#pragma unroll
    for (int ii = 0; ii < 21; ++ii) {
        int i = tid + ii * 256;
        if (i < 5184) {
            int icp = i / 324, hp = i - icp * 324;
            int hy = hp / 18, hx = hp - hy * 18;
            int gy = ty + hy - 1, gx = tx + hx - 1;
            bool valid = ((unsigned)gy < IMG) && ((unsigned)gx < IMG);
            const float* fs = feat + ((size_t)(bb * CIN + icp * 2)) * HWSZ
                                   + (valid ? (gy * IMG + gx) : 0);
            pv0[ii] = valid ? fs[0]    : 0.0f;
            pv1[ii] = valid ? fs[HWSZ] : 0.0f;
        }
    }

#pragma unroll 1
    for (int icc = 0; icc < 8; ++icc) {
        __syncthreads();                    // prev chunk's frag reads complete
        // ---- stage A: 36864 B = 2304 int4 (wpk is L2-hot)
        {
            const int4v* asrc = asrc_base + (size_t)icc * 2304;
            int4v* adst = (int4v*)Alds;
#pragma unroll
            for (int i = 0; i < 9; ++i)
                adst[tid + i * 256] = asrc[tid + i * 256];
        }
        // ---- write prefetched B: convert + split to LDS
#pragma unroll
        for (int ii = 0; ii < 21; ++ii) {
            int i = tid + ii * 256;
            if (i < 5184) {
                int icp = i / 324, hp = i - icp * 324;
                float v0 = pv0[ii], v1 = pv1[ii];
                unsigned short h0 = f2bf(v0), h1 = f2bf(v1);
                unsigned short m0 = f2bf(v0 - bf2f(h0)), m1 = f2bf(v1 - bf2f(h1));
                Bd[hp * 34 + icp]      = (unsigned)h0 | ((unsigned)h1 << 16);
                Bd[hp * 34 + 16 + icp] = (unsigned)m0 | ((unsigned)m1 << 16);
            }
        }
        __syncthreads();

        // ---- issue next chunk's B loads (overlap with compute below)
        if (icc < 7) {
#pragma unroll
            for (int ii = 0; ii < 21; ++ii) {
                int i = tid + ii * 256;
                if (i < 5184) {
                    int icp = i / 324, hp = i - icp * 324;
                    int hy = hp / 18, hx = hp - hy * 18;
                    int gy = ty + hy - 1, gx = tx + hx - 1;
                    bool valid = ((unsigned)gy < IMG) && ((unsigned)gx < IMG);
                    const float* fs = feat
                        + ((size_t)(bb * CIN + (icc + 1) * 32 + icp * 2)) * HWSZ
                        + (valid ? (gy * IMG + gx) : 0);
                    pv0[ii] = valid ? fs[0]    : 0.0f;
                    pv1[ii] = valid ? fs[HWSZ] : 0.0f;
                }
            }
        }

#pragma unroll
        for (int tap = 0; tap < 9; ++tap) {
            const int sy = tap / 3, sx = tap % 3;
            frag_u Af[2][2], Bf[2][4];
#pragma unroll
            for (int t = 0; t < 2; ++t) {
#pragma unroll
                for (int mi = 0; mi < 2; ++mi) {
                    const char* base = (const char*)Alds + (tap * 32 + mi * 16) * 128;
                    Af[t][mi].u[0] = *(const u64*)(base + aoff[t][0]);
                    Af[t][mi].u[1] = *(const u64*)(base + aoff[t][1]);
                }
#pragma unroll
                for (int nj = 0; nj < 4; ++nj) {
                    int pos = (w * 4 + nj + sy) * 18 + (l15 + sx);
                    const short* bp = &Blds[pos * 68 + t * 32 + quad * 8];
                    Bf[t][nj].u[0] = *(const u64*)bp;
                    Bf[t][nj].u[1] = *(const u64*)(bp + 4);
                }
            }
#pragma unroll
            for (int mi = 0; mi < 2; ++mi)
#pragma unroll
                for (int nj = 0; nj < 4; ++nj) {
                    acc[mi][nj] = __builtin_amdgcn_mfma_f32_16x16x32_bf16(
                        Af[0][mi].s8, Bf[0][nj].s8, acc[mi][nj], 0, 0, 0);
                    acc[mi][nj] = __builtin_amdgcn_mfma_f32_16x16x32_bf16(
                        Af[0][mi].s8, Bf[1][nj].s8, acc[mi][nj], 0, 0, 0);
                    acc[mi][nj] = __builtin_amdgcn_mfma_f32_16x16x32_bf16(
                        Af[1][mi].s8, Bf[0][nj].s8, acc[mi][nj], 0, 0, 0);
                    acc[mi][nj] = __builtin_amdgcn_mfma_f32_16x16x32_bf16(
                        Af[1][mi].s8, Bf[1][nj].s8, acc[mi][nj], 0, 0, 0);
                }
        }
    }

    // ---- epilogue: BN + ReLU.  C/D: col(l15)=px col, row(quad*4+r)=oc.
#pragma unroll
    for (int nj = 0; nj < 4; ++nj) {
        const int gy = ty + w * 4 + nj, gx = tx + l15;
#pragma unroll
        for (int mi = 0; mi < 2; ++mi)
#pragma unroll
            for (int r = 0; r < 4; ++r) {
                const int oc = oc0 + mi * 16 + quad * 4 + r;
                float v = acc[mi][nj][r] + b1[oc];
                v = (v - mean[oc]) * (gamma[oc] / sqrtf(var[oc] + 1e-5f)) + beta[oc];
                y1[((size_t)(bb * COUT1 + oc)) * HWSZ + gy * IMG + gx] = fmaxf(v, 0.0f);
            }
    }
}

// ===========================================================================
// ===========================  SHARED TAIL  =================================
// ===========================================================================

// ---------------------------------------------------------------------------
// conv2 v2: grouped 3x3, SEL channels only.  32x16 px tile, 2 px/thread,
// LDS [16][18][40] (stride 40 = 8 mod 32), float2 tap reads, staging indices
// precomputed once, w2 pointers block-uniform (scalar loads).
// ---------------------------------------------------------------------------
__global__ __launch_bounds__(256, 2) void conv2_kernel(
    const float* __restrict__ y1, const float* __restrict__ w2,
    const float* __restrict__ b2, float* __restrict__ out) {
    const int KH[6]   = {1, 1, 2, 1, 2, 4};
    const int REG[6]  = {OFF_LMAP, OFF_JMAP, OFF_JOFF, OFF_CMAP, OFF_COFF, OFF_LVEC};
    const int SIGF[6] = {1, 1, 0, 1, 0, 0};

    const int bz = blockIdx.z;
    const int b  = bz / 6;
    const int h  = bz % 6;
    const int k  = KH[h];
    const int tx = blockIdx.x * 32, ty = blockIdx.y * 16;
    const int lx = threadIdx.x, ly = threadIdx.y;   // lx: column pair, ly: row
    const int tid = ly * 16 + lx;

    __shared__ float tin[16][18][40];               // 46080 B; 34 cols used
    float* const tinf = &tin[0][0][0];
    float accv[4][2] = {{0.f,0.f},{0.f,0.f},{0.f,0.f},{0.f,0.f}};

    const float* yb = y1 + ((size_t)(b * COUT1 + h * 64)) * HWSZ;

    // staging slots: 18 rows x 34 cols = 612 elements, <=3 per thread
    bool sok[3], sval[3];
    int  soff[3], sidx[3];
#pragma unroll
    for (int j = 0; j < 3; ++j) {
        int idx = tid + j * 256;
        sok[j] = (idx < 612);
        int r = idx / 34, col = idx - r * 34;
        int gy = ty - 1 + r, gx = tx - 1 + col;
        sval[j] = sok[j] && ((unsigned)gy < (unsigned)IMG) && ((unsigned)gx < (unsigned)IMG);
        soff[j] = sval[j] ? (gy * IMG + gx) : 0;
        sidx[j] = r * 40 + col;
    }

    for (int ic0 = 0; ic0 < 64; ic0 += 16) {
        __syncthreads();
#pragma unroll
        for (int j = 0; j < 3; ++j) {
            if (sok[j]) {
                const float* yp = yb + (size_t)ic0 * HWSZ + soff[j];
                float* tp = tinf + sidx[j];
#pragma unroll 4
                for (int c = 0; c < 16; ++c)
                    tp[c * 720] = sval[j] ? yp[(size_t)c * HWSZ] : 0.0f;
            }
        }
        __syncthreads();

        const float* tb = tinf + ly * 40 + 2 * lx;
#pragma unroll 2
        for (int c = 0; c < 16; ++c) {
            const float* tc = tb + c * 720;
            float n[3][4];
#pragma unroll
            for (int r = 0; r < 3; ++r) {
                float2 u = *(const float2*)(tc + r * 40);
                float2 v = *(const float2*)(tc + r * 40 + 2);
                n[r][0] = u.x; n[r][1] = u.y; n[r][2] = v.x; n[r][3] = v.y;
            }
#pragma unroll
            for (int o = 0; o < 4; ++o) {
                if (o < k) {
                    const float* wp = w2 + ((size_t)((h * 4 + o) * 64 + (ic0 + c))) * 9;
                    float a0 = accv[o][0], a1 = accv[o][1];
#pragma unroll
                    for (int r = 0; r < 3; ++r) {
                        float w0 = wp[3*r], w1 = wp[3*r+1], w2v = wp[3*r+2];
                        a0 = fmaf(n[r][0], w0, a0);
                        a1 = fmaf(n[r][1], w0, a1);
                        a0 = fmaf(n[r][1], w1, a0);
                        a1 = fmaf(n[r][2], w1, a1);
                        a0 = fmaf(n[r][2], w2v, a0);
                        a1 = fmaf(n[r][3], w2v, a1);
                    }
                    accv[o][0] = a0; accv[o][1] = a1;
                }
            }
        }
    }

    const int p = (ty + ly) * IMG + tx + 2 * lx;
#pragma unroll
    for (int o = 0; o < 4; ++o) {
        if (o < k) {
            float v0 = accv[o][0] + b2[h * 4 + o];
            float v1 = accv[o][1] + b2[h * 4 + o];
            if (SIGF[h]) { v0 = sigmoidf(v0); v1 = sigmoidf(v1); }
            size_t base = (size_t)REG[h] + ((size_t)(b * k + o)) * HWSZ + p;
            out[base]     = v0;
            out[base + 1] = v1;
        }
    }
}

// ---------------------------------------------------------------------------
// NMS on jmap + pack sort keys (value_bits<<32 | ~index  == lax.top_k order).
// ---------------------------------------------------------------------------
__global__ void nms_pack_kernel(const float* __restrict__ out,
                                u64* __restrict__ jsort,
                                u64* __restrict__ csort) {
    const int g = blockIdx.x;           // 0..399
    const int b = g / 100, q = g % 100;
    const int p = q * 256 + threadIdx.x;
    const float* jm = out + OFF_JMAP + (size_t)b * HWSZ;
    const float* cm = out + OFF_CMAP + (size_t)b * HWSZ;

    const int x = p % IMG, y = p / IMG;
    float v = jm[p];
    float mx = v;
#pragma unroll
    for (int dy = -1; dy <= 1; ++dy)
#pragma unroll
        for (int dx = -1; dx <= 1; ++dx) {
            int nx = x + dx, ny = y + dy;
            if (nx >= 0 && nx < IMG && ny >= 0 && ny < IMG)
                mx = fmaxf(mx, jm[ny * IMG + nx]);
        }
    float nmsv = (v == mx) ? v : 0.0f;

    u64 tagj = ((u64)__float_as_uint(nmsv) << 32)
             | (u64)(0xFFFFFFFFu - (unsigned)p);
    u64 tagc = ((u64)__float_as_uint(cm[p]) << 32)
             | (u64)(0xFFFFFFFFu - (unsigned)p);
    jsort[(size_t)b * 32768 + p] = tagj;
    csort[(size_t)b * 32768 + p] = tagc;
    if (q < 28) {                        // pad 25600..32767 with minimal keys
        int pp = 25600 + q * 256 + threadIdx.x;
        jsort[(size_t)b * 32768 + pp] = 0ull;
        csort[(size_t)b * 32768 + pp] = 0ull;
    }
}

// ---------------------------------------------------------------------------
// Hybrid bitonic sort, descending, 8 arrays x 32768 u64.
// ---------------------------------------------------------------------------
__global__ __launch_bounds__(1024) void sort64_ldsA(u64* __restrict__ buf) {
    __shared__ u64 s[8192];
    const size_t base = (size_t)blockIdx.x * 8192;   // 32 chunks (8 arrays x 4)
    const int cbase = (blockIdx.x & 3) * 8192;       // chunk offset within array
    for (int i = threadIdx.x; i < 8192; i += 1024) s[i] = buf[base + i];
    for (int k = 2; k <= 8192; k <<= 1)
        for (int j = k >> 1; j > 0; j >>= 1) {
            __syncthreads();
            for (int t = threadIdx.x; t < 4096; t += 1024) {
                int i = ((t & ~(j - 1)) << 1) | (t & (j - 1));
                int l = i | j;
                bool desc = (((i + cbase) & k) == 0);
                u64 x = s[i], y = s[l];
                if (desc ? (x < y) : (x > y)) { s[i] = y; s[l] = x; }
            }
        }
    __syncthreads();
    for (int i = threadIdx.x; i < 8192; i += 1024) buf[base + i] = s[i];
}

__global__ void sort64_gstep(u64* __restrict__ buf, int k, int j) {
    int t = blockIdx.x * 256 + threadIdx.x;          // 8 arrays * 16384 pairs
    int arr = t >> 14, p = t & 16383;
    int i = ((p & ~(j - 1)) << 1) | (p & (j - 1));
    int l = i | j;
    bool desc = ((i & k) == 0);
    u64* a = buf + (size_t)arr * 32768;
    u64 x = a[i], y = a[l];
    if (desc ? (x < y) : (x > y)) { a[i] = y; a[l] = x; }
}

__global__ __launch_bounds__(1024) void sort64_ldsB(u64* __restrict__ buf, int k) {
    __shared__ u64 s[8192];
    const size_t base = (size_t)blockIdx.x * 8192;
    const int cbase = (blockIdx.x & 3) * 8192;
    for (int i = threadIdx.x; i < 8192; i += 1024) s[i] = buf[base + i];
    for (int j = 4096; j > 0; j >>= 1) {
        __syncthreads();
        for (int t = threadIdx.x; t < 4096; t += 1024) {
            int i = ((t & ~(j - 1)) << 1) | (t & (j - 1));
            int l = i | j;
            bool desc = (((i + cbase) & k) == 0);
            u64 x = s[i], y = s[l];
            if (desc ? (x < y) : (x > y)) { s[i] = y; s[l] = x; }
        }
    }
    __syncthreads();
    for (int i = threadIdx.x; i < 8192; i += 1024) buf[base + i] = s[i];
}

// Full-LDS bitonic sort, ascending, 8192 int keys (one array per block).
__global__ __launch_bounds__(1024) void sort32_lds(int* __restrict__ buf) {
    __shared__ int s[8192];
    int* a = buf + (size_t)blockIdx.x * 8192;
    for (int i = threadIdx.x; i < 8192; i += 1024) s[i] = a[i];
    for (int k = 2; k <= 8192; k <<= 1)
        for (int j = k >> 1; j > 0; j >>= 1) {
            __syncthreads();
            for (int t = threadIdx.x; t < 4096; t += 1024) {
                int i = ((t & ~(j - 1)) << 1) | (t & (j - 1));
                int l = i | j;
                bool asc = ((i & k) == 0);
                int x = s[i], y = s[l];
                if (asc ? (x > y) : (x < y)) { s[i] = y; s[l] = x; }
            }
        }
    __syncthreads();
    for (int i = threadIdx.x; i < 8192; i += 1024) a[i] = s[i];
}

// Top-300 junctions: coordinates + validity.
__global__ void junction_kernel(const u64* __restrict__ jsort,
                                const float* __restrict__ out,
                                float* __restrict__ junc, int* __restrict__ jvalid) {
    const int b = blockIdx.x;
    const int t = threadIdx.x;
    if (t >= 300) return;
    u64 key = jsort[(size_t)b * 32768 + t];
    float score  = __uint_as_float((unsigned)(key >> 32));
    unsigned idx = 0xFFFFFFFFu - (unsigned)(key & 0xFFFFFFFFull);
    const float* j0 = out + OFF_JOFF + (size_t)(b * 2) * HWSZ;
    const float* j1 = j0 + HWSZ;
    float jx = (float)(idx % IMG) + j0[idx] + 0.5f;
    float jy = (float)(idx / IMG) + j1[idx] + 0.5f;
    junc[(size_t)(b * 300 + t) * 2]     = clip_coord(jx);
    junc[(size_t)(b * 300 + t) * 2 + 1] = clip_coord(jy);
    jvalid[b * 300 + t] = (score >= 0.008f) ? 1 : 0;
}

// Top-5000 centers -> line endpoints -> nearest-junction keys.
__global__ void lines_kernel(const u64* __restrict__ csort,
                             const float* __restrict__ junc,
                             const int* __restrict__ jvalid,
                             const float* __restrict__ out,
                             int* __restrict__ lkeys) {
    const int b = blockIdx.y;
    const int t = blockIdx.x * 256 + threadIdx.x;

    __shared__ float jx[300], jy[300];
    __shared__ int jv[300];
    for (int i = threadIdx.x; i < 300; i += 256) {
        jx[i] = junc[(size_t)(b * 300 + i) * 2];
        jy[i] = junc[(size_t)(b * 300 + i) * 2 + 1];
        jv[i] = jvalid[b * 300 + i];
    }
    __syncthreads();

    if (t >= 8192) return;
    if (t >= 5000) { lkeys[b * 8192 + t] = 0x7FFFFFFF; return; }

    u64 key = csort[(size_t)b * 32768 + t];
    unsigned idx = 0xFFFFFFFFu - (unsigned)(key & 0xFFFFFFFFull);
    const float* c0 = out + OFF_COFF + (size_t)(b * 2) * HWSZ;
    const float* c1 = c0 + HWSZ;
    const float* lv = out + OFF_LVEC + (size_t)(b * 4) * HWSZ;

    float cx = (float)(idx % IMG) + c0[idx] + 0.5f;
    float cy = (float)(idx / IMG) + c1[idx] + 0.5f;
    float e0x = clip_coord(cx + lv[idx]);
    float e0y = clip_coord(cy + lv[HWSZ + idx]);
    float e1x = clip_coord(cx + lv[2 * HWSZ + idx]);
    float e1y = clip_coord(cy + lv[3 * HWSZ + idx]);

    float m1 = 1e18f, m2 = 1e18f;
    int i1 = 0, i2 = 0;
    for (int j = 0; j < 300; ++j) {
        if (jv[j]) {
            float dx = e0x - jx[j], dy = e0y - jy[j];
            float d = dx * dx + dy * dy;
            if (d < m1) { m1 = d; i1 = j; }
            dx = e1x - jx[j]; dy = e1y - jy[j];
            d = dx * dx + dy * dy;
            if (d < m2) { m2 = d; i2 = j; }
        }
    }
    int imin = min(i1, i2), imax = max(i1, i2);
    lkeys[b * 8192 + t] = (i1 != i2) ? (imin * 300 + imax) : BIGK;
}

// Dedup sorted keys -> line segments + mask.
__global__ void finalize_kernel(const int* __restrict__ lkeys,
                                const float* __restrict__ junc,
                                float* __restrict__ out) {
    const int b = blockIdx.y;
    const int t = blockIdx.x * 256 + threadIdx.x;
    if (t >= 5000) return;
    const int* lk = lkeys + b * 8192;
    int sk = lk[t];
    bool first = ((t == 0) || (sk != lk[t - 1])) && (sk < BIGK);
    int a  = first ? sk / 300 : 0;
    int bb = first ? sk % 300 : 0;
    float p0x = junc[(size_t)(b * 300 + a) * 2];
    float p0y = junc[(size_t)(b * 300 + a) * 2 + 1];
    float p1x = junc[(size_t)(b * 300 + bb) * 2];
    float p1y = junc[(size_t)(b * 300 + bb) * 2 + 1];
    if (p0y > p1y) {
        float tx = p0x; p0x = p1x; p1x = tx;
        float ty = p0y; p0y = p1y; p1y = ty;
    }
    size_t base = OFF_LOI + (size_t)(b * 5000 + t) * 4;
    out[base]     = p0x;
    out[base + 1] = p0y;
    out[base + 2] = p1x;
    out[base + 3] = p1y;
    out[OFF_MASK + b * 5000 + t] = first ? 1.0f : 0.0f;
}

extern "C" void kernel_launch(void* const* d_in, const int* in_sizes, int n_in,
                              void* d_out, int out_size, void* d_ws, size_t ws_size,
                              hipStream_t stream) {
    const float* feat  = (const float*)d_in[0];
    const float* w1    = (const float*)d_in[1];
    const float* b1    = (const float*)d_in[2];
    const float* gamma = (const float*)d_in[3];
    const float* beta  = (const float*)d_in[4];
    const float* mean  = (const float*)d_in[5];
    const float* var   = (const float*)d_in[6];
    const float* w2    = (const float*)d_in[7];
    const float* b2    = (const float*)d_in[8];
    float* out = (float*)d_out;
    char*  ws  = (char*)d_ws;

    if (ws_size < WS_NEED_LEGACY) return;

    float* y1 = (float*)(ws + WS_Y1);
    u64* jsort = (u64*)(ws + WS_JSORT);
    float* junc = (float*)(ws + WS_JUNC);
    int* jvalid = (int*)(ws + WS_JVAL);
    int* lkeys  = (int*)(ws + WS_LKEY);
    u64* csort = (u64*)(ws + WS_CSORT);
    short* wpk = (short*)(ws + WS_WPK);
    float* bns = (float*)(ws + WS_BNS);
    short* fpk = (short*)(ws + WS_FPK);

    if (ws_size >= WS_NEED_PK) {
        // 0a. pack conv1 weights (16B-slot swizzle) -> wpk
        wpack_pk_kernel<<<dim3(6912), dim3(256), 0, stream>>>(w1, wpk);
        // 0b. BN scale precompute (bitwise-identical to in-epilogue expr)
        bnscale_kernel<<<dim3(2), dim3(256), 0, stream>>>(gamma, var, bns);
        // 0c. pack feat into split-bf16 zero-bordered swizzled image -> fpk
        pack_feat_kernel<<<dim3(13122), dim3(256), 0, stream>>>(feat, fpk);
        // 1. conv1 + BN + ReLU via DMA-staged MFMA (3-product split)
        conv1_mfma_pk<<<dim3(4800), dim3(256), 0, stream>>>(
            fpk, wpk, b1, bns, beta, mean, y1);
    } else {
        // fallback: legacy path (workspace too small for fpk)
        wpack_kernel<<<dim3(6912), dim3(256), 0, stream>>>(w1, wpk);
        conv1_mfma<<<dim3(4800), dim3(256), 0, stream>>>(
            feat, wpk, b1, gamma, beta, mean, var, y1);
    }

    // 2. conv2 (grouped, SEL channels only) -> maps in d_out
    conv2_kernel<<<dim3(5, 10, NB * 6), dim3(16, 16), 0, stream>>>(y1, w2, b2, out);

    // 3. NMS + pack sort keys
    nms_pack_kernel<<<dim3(NB * 100), dim3(256), 0, stream>>>(out, jsort, csort);

    // 4. hybrid bitonic sort of 8 u64 arrays (4 jmap + 4 cmap, contiguous)
    sort64_ldsA<<<dim3(32), dim3(1024), 0, stream>>>(jsort);
    sort64_gstep<<<dim3(512), dim3(256), 0, stream>>>(jsort, 16384, 8192);
    sort64_ldsB<<<dim3(32), dim3(1024), 0, stream>>>(jsort, 16384);
    sort64_gstep<<<dim3(512), dim3(256), 0, stream>>>(jsort, 32768, 16384);
    sort64_gstep<<<dim3(512), dim3(256), 0, stream>>>(jsort, 32768, 8192);
    sort64_ldsB<<<dim3(32), dim3(1024), 0, stream>>>(jsort, 32768);

    // 5. junctions
    junction_kernel<<<dim3(NB), dim3(320), 0, stream>>>(jsort, out, junc, jvalid);

    // 6. line keys
    lines_kernel<<<dim3(32, NB), dim3(256), 0, stream>>>(csort, junc, jvalid, out, lkeys);

    // 7. sort line keys ascending (full LDS)
    sort32_lds<<<dim3(NB), dim3(1024), 0, stream>>>(lkeys);

    // 8. dedup + emit loi/mask
    finalize_kernel<<<dim3(20, NB), dim3(256), 0, stream>>>(lkeys, junc, out);
}

// Round 3
// 950.393 us; speedup vs baseline: 1.4374x; 1.0184x over previous
//
#include <hip/hip_runtime.h>
#include <math.h>

#define IMG   160
#define HWSZ  25600
#define NB    4
#define CIN   256
#define COUT1 384
#define BIGK  90000

// output offsets (in floats)
#define OFF_LMAP 0
#define OFF_JMAP 102400
#define OFF_JOFF 204800
#define OFF_CMAP 409600
#define OFF_COFF 512000
#define OFF_LVEC 716800
#define OFF_LOI  1126400
#define OFF_MASK 1206400

// workspace offsets (bytes)
static const size_t WS_Y1    = 0;
static const size_t WS_JSORT = (size_t)NB * COUT1 * HWSZ * 4;            // 157286400
static const size_t WS_CSORT = WS_JSORT + (size_t)NB * 32768 * 8;
static const size_t WS_JUNC  = WS_CSORT + (size_t)NB * 32768 * 8;
static const size_t WS_JVAL  = WS_JUNC + (size_t)NB * 300 * 2 * 4;
static const size_t WS_LKEY  = WS_JVAL + (size_t)NB * 300 * 4;
static const size_t WS_WPK   = WS_LKEY + (size_t)NB * 8192 * 4;
// Wpack: 12 octiles * 8 icc * 9 taps * 32 ocl * 64 shorts * 2 B = 3,538,944
static const size_t WS_AFTER_WPK = WS_WPK + (size_t)12 * 8 * 9 * 32 * 64 * 2;
static const size_t WS_BNS   = WS_AFTER_WPK;                             // 384 f32
static const size_t WS_JM    = WS_BNS + 384 * 4;                         // NB*300 u64
static const size_t WS_CM    = WS_JM + (size_t)NB * 300 * 8;             // NB*5000 u64
static const size_t WS_FPK   = WS_CM + (size_t)NB * 5000 * 8;
static const size_t WS_NEED_MIN = WS_FPK;                                // legacy floor
// packed feat: [b][icc 8][py 162][px 162][128 B]  (zero border, slot-swizzled)
static const size_t WS_NEED_PK = WS_FPK + (size_t)NB * 8 * 162 * 162 * 128;  // ~258 MB

typedef unsigned long long u64;
typedef __attribute__((ext_vector_type(8))) short short8;
typedef __attribute__((ext_vector_type(4))) float f32x4;
typedef __attribute__((ext_vector_type(4))) int int4v;

union frag_u { short8 s8; u64 u[2]; int4v v; };

__device__ __forceinline__ float clip_coord(float v) {
    return fminf(fmaxf(v, 0.0f), 159.9999f);
}
__device__ __forceinline__ float sigmoidf(float v) {
    return 1.0f / (1.0f + expf(-v));
}
__device__ __forceinline__ unsigned short f2bf(float f) {   // RNE
    unsigned u = __float_as_uint(f);
    return (unsigned short)((u + 0x7FFFu + ((u >> 16) & 1u)) >> 16);
}
__device__ __forceinline__ float bf2f(unsigned short h) {
    return __uint_as_float((unsigned)h << 16);
}

// async 16B global -> LDS (DMA). LDS dest must be wave-uniform base; HW adds lane*16.
__device__ __forceinline__ void async_copy16(void* lds, const void* g) {
    __builtin_amdgcn_global_load_lds(
        (const __attribute__((address_space(1))) unsigned int*)g,
        (__attribute__((address_space(3))) unsigned int*)lds, 16, 0, 0);
}

// ===========================================================================
// ============================  NEW (pk) PATH  ==============================
// ===========================================================================

// ---------------------------------------------------------------------------
// Pre-pack w1 for the DMA+b128 conv1 (+ BN scale fold in last block):
//   Wpack[octile 12][icc 8][tap 9][ocl 32][8 phys 16B-slots][8 shorts]
//   physical 16B slot p16 holds LOGICAL slot p16 ^ (ocl & 7);
//   logical slot l16 = t*4+quad -> term t, channels quad*8..quad*8+7 (k-order)
// ---------------------------------------------------------------------------
__global__ void wpack_pk_kernel(const float* __restrict__ w1, short* __restrict__ wpk,
                                const float* __restrict__ gamma,
                                const float* __restrict__ var,
                                float* __restrict__ bns) {
    if (blockIdx.x == 6912) {        // folded bnscale: bitwise-same expression
        for (int i = threadIdx.x; i < COUT1; i += 256)
            bns[i] = gamma[i] / sqrtf(var[i] + 1e-5f);
        return;
    }
    int e = blockIdx.x * 256 + threadIdx.x;      // 12*8*9*32*64 = 1,769,472 exact
    int row = e >> 6, sp = e & 63;
    int ocl = row & 31;
    int tap = (row >> 5) % 9;
    int icc = (row / 288) & 7;
    int octile = row / 2304;
    int p16 = sp >> 3, j = sp & 7;
    int l16 = p16 ^ (ocl & 7);                   // logical 16B slot
    int ql = l16 * 8 + j;                        // logical short index 0..63
    int term = ql >> 5, icl = ql & 31;
    int oc = octile * 32 + ocl, ic = icc * 32 + icl;
    float a = w1[((size_t)oc * CIN + ic) * 9 + tap];
    unsigned short hi = f2bf(a);
    wpk[e] = (term == 0) ? (short)hi : (short)f2bf(a - bf2f(hi));
}

// ---------------------------------------------------------------------------
// Pre-pack feat into split-bf16, zero-bordered, slot-swizzled global image:
//   fpk[b][icc][py 0..161][px 0..161][128 B]
//   physical 16B slot p holds logical slot p ^ s, s = (2*py+px)&7.
//   logical slot l: term t=l>>2, channels (l&3)*8 .. +7 of group icc (k-order).
// ---------------------------------------------------------------------------
__global__ __launch_bounds__(256) void pack_feat_kernel(
    const float* __restrict__ feat, short* __restrict__ fpk) {
    const int tid = threadIdx.x;
    const int c4  = (tid >> 4) & 3;                       // channel quarter 0..3
    const int r0  = (tid & 15) | (((tid >> 6) & 3) << 4); // 0..63
    const int rest = blockIdx.x * 64 + r0;   // (b*8+icc)*26244 + py*162 + px
    const int px = rest % 162;
    const int t2 = rest / 162;
    const int py = t2 % 162;
    const int bi = t2 / 162;                 // b*8 + icc
    const int s  = (2 * py + px) & 7;
    const int gy = py - 1, gx = px - 1;
    const bool valid = ((unsigned)gy < (unsigned)IMG) && ((unsigned)gx < (unsigned)IMG);
    const float* fs = feat + (size_t)(bi * 32 + c4 * 8) * HWSZ
                           + (valid ? gy * IMG + gx : 0);
    unsigned hi4[4], lo4[4];
#pragma unroll
    for (int j2 = 0; j2 < 4; ++j2) {
        float va = valid ? fs[(size_t)(2 * j2) * HWSZ]     : 0.0f;
        float vb = valid ? fs[(size_t)(2 * j2 + 1) * HWSZ] : 0.0f;
        unsigned short ha = f2bf(va), hb = f2bf(vb);
        unsigned short la = f2bf(va - bf2f(ha)), lb = f2bf(vb - bf2f(hb));
        hi4[j2] = (unsigned)ha | ((unsigned)hb << 16);
        lo4[j2] = (unsigned)la | ((unsigned)lb << 16);
    }
    const int p0 = c4 ^ s;            // physical slot holding logical l=c4 (term0)
    const int p1 = (c4 | 4) ^ s;      // physical slot holding logical l=c4+4 (term1)
    int4v* base = (int4v*)(fpk + (size_t)rest * 64);
    base[p0] = (int4v){ (int)hi4[0], (int)hi4[1], (int)hi4[2], (int)hi4[3] };
    base[p1] = (int4v){ (int)lo4[0], (int)lo4[1], (int)lo4[2], (int)lo4[3] };
}

// ---------------------------------------------------------------------------
// conv1 via MFMA implicit GEMM, 3-product bf16 split, register-prefetch
// pipeline: B(icc+1) global->reg issued BEFORE compute(icc) (latency hides
// under ~4200cyc of MFMA), written reg->LDS in a short post-barrier phase
// together with the A DMA (L2-hot wpk).  Compute identical to round 2.
// ---------------------------------------------------------------------------
__global__ __launch_bounds__(256, 2) void conv1_mfma_pk(
    const short* __restrict__ fpk, const short* __restrict__ wpk,
    const float* __restrict__ b1, const float* __restrict__ bns,
    const float* __restrict__ beta, const float* __restrict__ mean,
    float* __restrict__ y1) {
    const int bid   = blockIdx.x;                 // 0..4799
    const int slot  = bid >> 3;                   // 0..599
    const int tile  = (bid & 7) + ((slot / 12) << 3);   // XCD-local tile set
    const int octile = slot - (slot / 12) * 12;   // 0..11
    const int bb = tile / 100, tt = tile % 100;
    const int ty = (tt / 10) * 16, tx = (tt % 10) * 16;
    const int oc0 = octile * 32;
    const int tid  = threadIdx.x;
    const int w    = tid >> 6;              // wave: px rows w*4..w*4+3
    const int lane = tid & 63;
    const int quad = lane >> 4;
    const int l15  = lane & 15;
    const int wbase = tid & 192;            // w*64, wave-uniform

    __shared__ __align__(16) short Alds[288 * 64];   // 36864 B
    __shared__ __align__(16) short Blds[324 * 64];   // 41472 B

    int aoff[2];
#pragma unroll
    for (int t = 0; t < 2; ++t)
        aoff[t] = l15 * 128 + ((((t << 2) | quad) ^ (l15 & 7)) << 4);

    f32x4 acc[2][4];
#pragma unroll
    for (int mi = 0; mi < 2; ++mi)
#pragma unroll
        for (int nj = 0; nj < 4; ++nj) acc[mi][nj] = (f32x4){0.f, 0.f, 0.f, 0.f};

    const char* asrc0 = (const char*)wpk + (size_t)(octile * 8) * 36864;

    // B global byte-offsets within one icc image (10 chunks + remainder)
    int boff[10];
#pragma unroll
    for (int it = 0; it < 10; ++it) {
        int k = it * 256 + tid;
        int hy = (int)((unsigned)k / 144u);
        int r  = k - hy * 144;
        boff[it] = hy * (162 * 128) + r * 16;
    }
    const int roff = 17 * (162 * 128) + (112 + (tid & 31)) * 16;
    const char* bsrc0 = (const char*)fpk
        + (((size_t)(bb * 8) * 162 + ty) * 162 + tx) * 128;
    const size_t bstride = (size_t)162 * 162 * 128;   // per-icc stride

    // ---- stage icc=0 via DMA
    {
#pragma unroll
        for (int i = 0; i < 9; ++i)
            async_copy16((char*)Alds + (size_t)(i * 256 + wbase) * 16,
                         asrc0 + (size_t)(i * 256 + tid) * 16);
#pragma unroll
        for (int it = 0; it < 10; ++it)
            async_copy16((char*)Blds + (size_t)(it * 256 + wbase) * 16,
                         bsrc0 + boff[it]);
        if (tid < 32) {
            const int4v vv = *(const int4v*)(bsrc0 + roff);
            *(int4v*)((char*)Blds + (size_t)(2560 + tid) * 16) = vv;
        }
    }
    __syncthreads();                        // drains vmcnt/lgkmcnt

    int4v pvB[10]; int4v pvR;
#pragma unroll 1
    for (int icc = 0; icc < 8; ++icc) {
        // ---- issue next B tile into registers (overlaps with compute below)
        if (icc < 7) {
            const char* bs = bsrc0 + (size_t)(icc + 1) * bstride;
#pragma unroll
            for (int it = 0; it < 10; ++it)
                pvB[it] = *(const int4v*)(bs + boff[it]);
            pvR = *(const int4v*)(bs + roff);
        }

        // ---- compute icc (unchanged from round 2; bitwise-identical)
#pragma unroll
        for (int sx = 0; sx < 3; ++sx) {
            frag_u Bf[2][6];                // rows w*4 .. w*4+5, this sx column
#pragma unroll
            for (int t = 0; t < 2; ++t)
#pragma unroll
                for (int rr = 0; rr < 6; ++rr) {
                    int pos = (w * 4 + rr) * 18 + (l15 + sx);
                    const char* bp = (const char*)Blds + (size_t)pos * 128
                        + ((((t << 2) | quad) ^ (pos & 7)) << 4);
                    Bf[t][rr].v = *(const int4v*)bp;
                }
#pragma unroll
            for (int sy = 0; sy < 3; ++sy) {
                const int tap = sy * 3 + sx;
                frag_u Af[2][2];
#pragma unroll
                for (int t = 0; t < 2; ++t)
#pragma unroll
                    for (int mi = 0; mi < 2; ++mi) {
                        const char* ap = (const char*)Alds
                            + (size_t)(tap * 32 + mi * 16) * 128 + aoff[t];
                        Af[t][mi].v = *(const int4v*)ap;
                    }
#pragma unroll
                for (int mi = 0; mi < 2; ++mi)
#pragma unroll
                    for (int nj = 0; nj < 4; ++nj) {
                        acc[mi][nj] = __builtin_amdgcn_mfma_f32_16x16x32_bf16(
                            Af[0][mi].s8, Bf[0][nj + sy].s8, acc[mi][nj], 0, 0, 0);
                        acc[mi][nj] = __builtin_amdgcn_mfma_f32_16x16x32_bf16(
                            Af[0][mi].s8, Bf[1][nj + sy].s8, acc[mi][nj], 0, 0, 0);
                        acc[mi][nj] = __builtin_amdgcn_mfma_f32_16x16x32_bf16(
                            Af[1][mi].s8, Bf[0][nj + sy].s8, acc[mi][nj], 0, 0, 0);
                    }
            }
        }

        // ---- write phase: frag reads done -> A DMA (L2-hot) + B reg->LDS
        if (icc < 7) {
            __syncthreads();
            {
                const char* as = asrc0 + (size_t)(icc + 1) * 36864;
#pragma unroll
                for (int i = 0; i < 9; ++i)
                    async_copy16((char*)Alds + (size_t)(i * 256 + wbase) * 16,
                                 as + (size_t)(i * 256 + tid) * 16);
            }
#pragma unroll
            for (int it = 0; it < 10; ++it)
                *(int4v*)((char*)Blds + (size_t)(it * 256 + tid) * 16) = pvB[it];
            if (tid < 32)
                *(int4v*)((char*)Blds + (size_t)(2560 + tid) * 16) = pvR;
            __syncthreads();                // drains A-DMA + B writes
        }
    }

    // ---- epilogue: BN + ReLU.  C/D: col(l15)=px col, row(quad*4+r)=oc.
#pragma unroll
    for (int nj = 0; nj < 4; ++nj) {
        const int gy = ty + w * 4 + nj, gx = tx + l15;
#pragma unroll
        for (int mi = 0; mi < 2; ++mi)
#pragma unroll
            for (int r = 0; r < 4; ++r) {
                const int oc = oc0 + mi * 16 + quad * 4 + r;
                float v = acc[mi][nj][r] + b1[oc];
                v = (v - mean[oc]) * bns[oc] + beta[oc];
                y1[((size_t)(bb * COUT1 + oc)) * HWSZ + gy * IMG + gx] = fmaxf(v, 0.0f);
            }
    }
}

// ===========================================================================
// =======================  LEGACY PATH (ws fallback)  =======================
// ===========================================================================

__global__ void wpack_kernel(const float* __restrict__ w1, short* __restrict__ wpk) {
    int e = blockIdx.x * 256 + threadIdx.x;      // 12*8*9*32*64 = 1,769,472 exact
    int row = e >> 6, sp = e & 63;
    int ocl = row & 31;
    int tap = (row >> 5) % 9;
    int icc = (row / 288) & 7;
    int octile = row / 2304;
    int s = (sp >> 2) ^ (ocl & 15);              // logical slot
    int ql = s * 4 + (sp & 3);                   // logical short index 0..63
    int term = ql >> 5, icl = ql & 31;
    int oc = octile * 32 + ocl, ic = icc * 32 + icl;
    float a = w1[((size_t)oc * CIN + ic) * 9 + tap];
    unsigned short hi = f2bf(a);
    wpk[e] = (term == 0) ? (short)hi : (short)f2bf(a - bf2f(hi));
}

__global__ __launch_bounds__(256, 2) void conv1_mfma(
    const float* __restrict__ feat, const short* __restrict__ wpk,
    const float* __restrict__ b1, const float* __restrict__ gamma,
    const float* __restrict__ beta, const float* __restrict__ mean,
    const float* __restrict__ var, float* __restrict__ y1) {
    const int bid   = blockIdx.x;                 // 0..4799
    const int slot  = bid >> 3;                   // 0..599
    const int tile  = (bid & 7) + ((slot / 12) << 3);   // XCD-local tile set
    const int octile = slot - (slot / 12) * 12;   // 0..11
    const int bb = tile / 100, tt = tile % 100;
    const int ty = (tt / 10) * 16, tx = (tt % 10) * 16;
    const int oc0 = octile * 32;
    const int tid  = threadIdx.x;
    const int w    = tid >> 6;              // wave: px rows w*4..w*4+3
    const int lane = tid & 63;
    const int quad = lane >> 4;
    const int l15  = lane & 15;

    __shared__ short Alds[288 * 64];        // [tap*32+ocl][64 sh, perm'd] 36864 B
    __shared__ short Blds[324 * 68];        // [hy*18+hx][t0 32|t1 32|pad] 44064 B

    int aoff[2][2];
#pragma unroll
    for (int t = 0; t < 2; ++t)
#pragma unroll
        for (int h = 0; h < 2; ++h)
            aoff[t][h] = l15 * 128 + (((t * 8 + quad * 2 + h) ^ l15) * 8);

    f32x4 acc[2][4];
#pragma unroll
    for (int mi = 0; mi < 2; ++mi)
#pragma unroll
        for (int nj = 0; nj < 4; ++nj) acc[mi][nj] = (f32x4){0.f, 0.f, 0.f, 0.f};

    const int4v* asrc_base = (const int4v*)wpk + (size_t)(octile * 8) * 2304;
    unsigned* Bd = (unsigned*)Blds;

    // B prefetch registers: 21 iters x 2 floats
    float pv0[21], pv1[21];

    // ---- prefetch chunk 0
#pragma unroll
    for (int ii = 0; ii < 21; ++ii) {
        int i = tid + ii * 256;
        if (i < 5184) {
            int icp = i / 324, hp = i - icp * 324;
            int hy = hp / 18, hx = hp - hy * 18;
            int gy = ty + hy - 1, gx = tx + hx - 1;
            bool valid = ((unsigned)gy < IMG) && ((unsigned)gx < IMG);
            const float* fs = feat + ((size_t)(bb * CIN + icp * 2)) * HWSZ
                                   + (valid ? (gy * IMG + gx) : 0);
            pv0[ii] = valid ? fs[0]    : 0.0f;
            pv1[ii] = valid ? fs[HWSZ] : 0.0f;
        }
    }

#pragma unroll 1
    for (int icc = 0; icc < 8; ++icc) {
        __syncthreads();                    // prev chunk's frag reads complete
        // ---- stage A: 36864 B = 2304 int4 (wpk is L2-hot)
        {
            const int4v* asrc = asrc_base + (size_t)icc * 2304;
            int4v* adst = (int4v*)Alds;
#pragma unroll
            for (int i = 0; i < 9; ++i)
                adst[tid + i * 256] = asrc[tid + i * 256];
        }
        // ---- write prefetched B: convert + split to LDS
#pragma unroll
        for (int ii = 0; ii < 21; ++ii) {
            int i = tid + ii * 256;
            if (i < 5184) {
                int icp = i / 324, hp = i - icp * 324;
                float v0 = pv0[ii], v1 = pv1[ii];
                unsigned short h0 = f2bf(v0), h1 = f2bf(v1);
                unsigned short m0 = f2bf(v0 - bf2f(h0)), m1 = f2bf(v1 - bf2f(h1));
                Bd[hp * 34 + icp]      = (unsigned)h0 | ((unsigned)h1 << 16);
                Bd[hp * 34 + 16 + icp] = (unsigned)m0 | ((unsigned)m1 << 16);
            }
        }
        __syncthreads();

        // ---- issue next chunk's B loads (overlap with compute below)
        if (icc < 7) {
#pragma unroll
            for (int ii = 0; ii < 21; ++ii) {
                int i = tid + ii * 256;
                if (i < 5184) {
                    int icp = i / 324, hp = i - icp * 324;
                    int hy = hp / 18, hx = hp - hy * 18;
                    int gy = ty + hy - 1, gx = tx + hx - 1;
                    bool valid = ((unsigned)gy < IMG) && ((unsigned)gx < IMG);
                    const float* fs = feat
                        + ((size_t)(bb * CIN + (icc + 1) * 32 + icp * 2)) * HWSZ
                        + (valid ? (gy * IMG + gx) : 0);
                    pv0[ii] = valid ? fs[0]    : 0.0f;
                    pv1[ii] = valid ? fs[HWSZ] : 0.0f;
                }
            }
        }

#pragma unroll
        for (int tap = 0; tap < 9; ++tap) {
            const int sy = tap / 3, sx = tap % 3;
            frag_u Af[2][2], Bf[2][4];
#pragma unroll
            for (int t = 0; t < 2; ++t) {
#pragma unroll
                for (int mi = 0; mi < 2; ++mi) {
                    const char* base = (const char*)Alds + (tap * 32 + mi * 16) * 128;
                    Af[t][mi].u[0] = *(const u64*)(base + aoff[t][0]);
                    Af[t][mi].u[1] = *(const u64*)(base + aoff[t][1]);
                }
#pragma unroll
                for (int nj = 0; nj < 4; ++nj) {
                    int pos = (w * 4 + nj + sy) * 18 + (l15 + sx);
                    const short* bp = &Blds[pos * 68 + t * 32 + quad * 8];
                    Bf[t][nj].u[0] = *(const u64*)bp;
                    Bf[t][nj].u[1] = *(const u64*)(bp + 4);
                }
            }
#pragma unroll
            for (int mi = 0; mi < 2; ++mi)
#pragma unroll
                for (int nj = 0; nj < 4; ++nj) {
                    acc[mi][nj] = __builtin_amdgcn_mfma_f32_16x16x32_bf16(
                        Af[0][mi].s8, Bf[0][nj].s8, acc[mi][nj], 0, 0, 0);
                    acc[mi][nj] = __builtin_amdgcn_mfma_f32_16x16x32_bf16(
                        Af[0][mi].s8, Bf[1][nj].s8, acc[mi][nj], 0, 0, 0);
                    acc[mi][nj] = __builtin_amdgcn_mfma_f32_16x16x32_bf16(
                        Af[1][mi].s8, Bf[0][nj].s8, acc[mi][nj], 0, 0, 0);
                    acc[mi][nj] = __builtin_amdgcn_mfma_f32_16x16x32_bf16(
                        Af[1][mi].s8, Bf[1][nj].s8, acc[mi][nj], 0, 0, 0);
                }
        }
    }

    // ---- epilogue: BN + ReLU.  C/D: col(l15)=px col, row(quad*4+r)=oc.
#pragma unroll
    for (int nj = 0; nj < 4; ++nj) {
        const int gy = ty + w * 4 + nj, gx = tx + l15;
#pragma unroll
        for (int mi = 0; mi < 2; ++mi)
#pragma unroll
            for (int r = 0; r < 4; ++r) {
                const int oc = oc0 + mi * 16 + quad * 4 + r;
                float v = acc[mi][nj][r] + b1[oc];
                v = (v - mean[oc]) * (gamma[oc] / sqrtf(var[oc] + 1e-5f)) + beta[oc];
                y1[((size_t)(bb * COUT1 + oc)) * HWSZ + gy * IMG + gx] = fmaxf(v, 0.0f);
            }
    }
}

// ===========================================================================
// ===========================  SHARED TAIL  =================================
// ===========================================================================

// ---------------------------------------------------------------------------
// conv2 v2: grouped 3x3, SEL channels only.  32x16 px tile, 2 px/thread,
// LDS [16][18][40], float2 tap reads, staging indices precomputed.
// ---------------------------------------------------------------------------
__global__ __launch_bounds__(256, 2) void conv2_kernel(
    const float* __restrict__ y1, const float* __restrict__ w2,
    const float* __restrict__ b2, float* __restrict__ out) {
    const int KH[6]   = {1, 1, 2, 1, 2, 4};
    const int REG[6]  = {OFF_LMAP, OFF_JMAP, OFF_JOFF, OFF_CMAP, OFF_COFF, OFF_LVEC};
    const int SIGF[6] = {1, 1, 0, 1, 0, 0};

    const int bz = blockIdx.z;
    const int b  = bz / 6;
    const int h  = bz % 6;
    const int k  = KH[h];
    const int tx = blockIdx.x * 32, ty = blockIdx.y * 16;
    const int lx = threadIdx.x, ly = threadIdx.y;   // lx: column pair, ly: row
    const int tid = ly * 16 + lx;

    __shared__ float tin[16][18][40];               // 46080 B; 34 cols used
    float* const tinf = &tin[0][0][0];
    float accv[4][2] = {{0.f,0.f},{0.f,0.f},{0.f,0.f},{0.f,0.f}};

    const float* yb = y1 + ((size_t)(b * COUT1 + h * 64)) * HWSZ;

    // staging slots: 18 rows x 34 cols = 612 elements, <=3 per thread
    bool sok[3], sval[3];
    int  soff[3], sidx[3];
#pragma unroll
    for (int j = 0; j < 3; ++j) {
        int idx = tid + j * 256;
        sok[j] = (idx < 612);
        int r = idx / 34, col = idx - r * 34;
        int gy = ty - 1 + r, gx = tx - 1 + col;
        sval[j] = sok[j] && ((unsigned)gy < (unsigned)IMG) && ((unsigned)gx < (unsigned)IMG);
        soff[j] = sval[j] ? (gy * IMG + gx) : 0;
        sidx[j] = r * 40 + col;
    }

    for (int ic0 = 0; ic0 < 64; ic0 += 16) {
        __syncthreads();
#pragma unroll
        for (int j = 0; j < 3; ++j) {
            if (sok[j]) {
                const float* yp = yb + (size_t)ic0 * HWSZ + soff[j];
                float* tp = tinf + sidx[j];
#pragma unroll 4
                for (int c = 0; c < 16; ++c)
                    tp[c * 720] = sval[j] ? yp[(size_t)c * HWSZ] : 0.0f;
            }
        }
        __syncthreads();

        const float* tb = tinf + ly * 40 + 2 * lx;
#pragma unroll 2
        for (int c = 0; c < 16; ++c) {
            const float* tc = tb + c * 720;
            float n[3][4];
#pragma unroll
            for (int r = 0; r < 3; ++r) {
                float2 u = *(const float2*)(tc + r * 40);
                float2 v = *(const float2*)(tc + r * 40 + 2);
                n[r][0] = u.x; n[r][1] = u.y; n[r][2] = v.x; n[r][3] = v.y;
            }
#pragma unroll
            for (int o = 0; o < 4; ++o) {
                if (o < k) {
                    const float* wp = w2 + ((size_t)((h * 4 + o) * 64 + (ic0 + c))) * 9;
                    float a0 = accv[o][0], a1 = accv[o][1];
#pragma unroll
                    for (int r = 0; r < 3; ++r) {
                        float w0 = wp[3*r], w1 = wp[3*r+1], w2v = wp[3*r+2];
                        a0 = fmaf(n[r][0], w0, a0);
                        a1 = fmaf(n[r][1], w0, a1);
                        a0 = fmaf(n[r][1], w1, a0);
                        a1 = fmaf(n[r][2], w1, a1);
                        a0 = fmaf(n[r][2], w2v, a0);
                        a1 = fmaf(n[r][3], w2v, a1);
                    }
                    accv[o][0] = a0; accv[o][1] = a1;
                }
            }
        }
    }

    const int p = (ty + ly) * IMG + tx + 2 * lx;
#pragma unroll
    for (int o = 0; o < 4; ++o) {
        if (o < k) {
            float v0 = accv[o][0] + b2[h * 4 + o];
            float v1 = accv[o][1] + b2[h * 4 + o];
            if (SIGF[h]) { v0 = sigmoidf(v0); v1 = sigmoidf(v1); }
            size_t base = (size_t)REG[h] + ((size_t)(b * k + o)) * HWSZ + p;
            out[base]     = v0;
            out[base + 1] = v1;
        }
    }
}

// ---------------------------------------------------------------------------
// NMS on jmap + pack sort keys (value_bits<<32 | ~index  == lax.top_k order).
// ---------------------------------------------------------------------------
__global__ void nms_pack_kernel(const float* __restrict__ out,
                                u64* __restrict__ jsort,
                                u64* __restrict__ csort) {
    const int g = blockIdx.x;           // 0..399
    const int b = g / 100, q = g % 100;
    const int p = q * 256 + threadIdx.x;
    const float* jm = out + OFF_JMAP + (size_t)b * HWSZ;
    const float* cm = out + OFF_CMAP + (size_t)b * HWSZ;

    const int x = p % IMG, y = p / IMG;
    float v = jm[p];
    float mx = v;
#pragma unroll
    for (int dy = -1; dy <= 1; ++dy)
#pragma unroll
        for (int dx = -1; dx <= 1; ++dx) {
            int nx = x + dx, ny = y + dy;
            if (nx >= 0 && nx < IMG && ny >= 0 && ny < IMG)
                mx = fmaxf(mx, jm[ny * IMG + nx]);
        }
    float nmsv = (v == mx) ? v : 0.0f;

    u64 tagj = ((u64)__float_as_uint(nmsv) << 32)
             | (u64)(0xFFFFFFFFu - (unsigned)p);
    u64 tagc = ((u64)__float_as_uint(cm[p]) << 32)
             | (u64)(0xFFFFFFFFu - (unsigned)p);
    jsort[(size_t)b * 32768 + p] = tagj;
    csort[(size_t)b * 32768 + p] = tagc;
    if (q < 28) {                        // pad 25600..32767 with minimal keys
        int pp = 25600 + q * 256 + threadIdx.x;
        jsort[(size_t)b * 32768 + pp] = 0ull;
        csort[(size_t)b * 32768 + pp] = 0ull;
    }
}

// ---------------------------------------------------------------------------
// Full bitonic sort of each 8192-chunk, ALL DESCENDING (32 chunks = 8 arrays
// x 4).  LDS skew (i + i>>4) kills the small-j b64 bank conflicts.
// ---------------------------------------------------------------------------
#define SK64(i) ((i) + ((i) >> 4))
__global__ __launch_bounds__(1024) void sort64_ldsA(u64* __restrict__ buf) {
    __shared__ u64 s[8192 + 512];
    const size_t base = (size_t)blockIdx.x * 8192;
    for (int i = threadIdx.x; i < 8192; i += 1024) s[SK64(i)] = buf[base + i];
    for (int k = 2; k <= 8192; k <<= 1)
        for (int j = k >> 1; j > 0; j >>= 1) {
            __syncthreads();
            for (int t = threadIdx.x; t < 4096; t += 1024) {
                int i = ((t & ~(j - 1)) << 1) | (t & (j - 1));
                int l = i | j;
                bool desc = ((i & k) == 0);
                u64 x = s[SK64(i)], y = s[SK64(l)];
                if (desc ? (x < y) : (x > y)) { s[SK64(i)] = y; s[SK64(l)] = x; }
            }
        }
    __syncthreads();
    for (int i = threadIdx.x; i < 8192; i += 1024) buf[base + i] = s[SK64(i)];
}

// ---------------------------------------------------------------------------
// Exact top-K extraction from 4 desc-sorted chunks via rank-merge.
// rank(e) = pos-in-own-chunk + sum over other chunks of count(key > e).
// Keys are unique (index embedded; pads 0ull never reach rank < K).
// ---------------------------------------------------------------------------
__device__ __forceinline__ int count_gt_desc(const u64* __restrict__ a, u64 e) {
    int cnt = 0;
#pragma unroll
    for (int st = 8192; st > 0; st >>= 1)
        if (cnt + st <= 8192 && a[cnt + st - 1] > e) cnt += st;
    return cnt;
}

__global__ void merge_topk_kernel(const u64* __restrict__ jsort,
                                  const u64* __restrict__ csort,
                                  u64* __restrict__ jm, u64* __restrict__ cm) {
    const int b = blockIdx.y;
    int t = blockIdx.x * 256 + threadIdx.x;
    const u64* src; u64* dst; int K, chunk, pos;
    if (t < 1200) {
        src = jsort + (size_t)b * 32768; dst = jm + (size_t)b * 300;
        K = 300; chunk = t / 300; pos = t - chunk * 300;
    } else {
        t -= 1200;
        if (t >= 20000) return;
        src = csort + (size_t)b * 32768; dst = cm + (size_t)b * 5000;
        K = 5000; chunk = t / 5000; pos = t - chunk * 5000;
    }
    u64 e = src[chunk * 8192 + pos];
    int rank = pos;
#pragma unroll
    for (int c = 0; c < 4; ++c)
        if (c != chunk) rank += count_gt_desc(src + c * 8192, e);
    if (rank < K) dst[rank] = e;
}

// Full-LDS bitonic sort, ascending, 8192 int keys (one array per block).
__global__ __launch_bounds__(1024) void sort32_lds(int* __restrict__ buf) {
    __shared__ int s[8192];
    int* a = buf + (size_t)blockIdx.x * 8192;
    for (int i = threadIdx.x; i < 8192; i += 1024) s[i] = a[i];
    for (int k = 2; k <= 8192; k <<= 1)
        for (int j = k >> 1; j > 0; j >>= 1) {
            __syncthreads();
            for (int t = threadIdx.x; t < 4096; t += 1024) {
                int i = ((t & ~(j - 1)) << 1) | (t & (j - 1));
                int l = i | j;
                bool asc = ((i & k) == 0);
                int x = s[i], y = s[l];
                if (asc ? (x > y) : (x < y)) { s[i] = y; s[l] = x; }
            }
        }
    __syncthreads();
    for (int i = threadIdx.x; i < 8192; i += 1024) a[i] = s[i];
}

// Top-300 junctions: coordinates + validity (from merged jm).
__global__ void junction_kernel(const u64* __restrict__ jmk,
                                const float* __restrict__ out,
                                float* __restrict__ junc, int* __restrict__ jvalid) {
    const int b = blockIdx.x;
    const int t = threadIdx.x;
    if (t >= 300) return;
    u64 key = jmk[(size_t)b * 300 + t];
    float score  = __uint_as_float((unsigned)(key >> 32));
    unsigned idx = 0xFFFFFFFFu - (unsigned)(key & 0xFFFFFFFFull);
    const float* j0 = out + OFF_JOFF + (size_t)(b * 2) * HWSZ;
    const float* j1 = j0 + HWSZ;
    float jx = (float)(idx % IMG) + j0[idx] + 0.5f;
    float jy = (float)(idx / IMG) + j1[idx] + 0.5f;
    junc[(size_t)(b * 300 + t) * 2]     = clip_coord(jx);
    junc[(size_t)(b * 300 + t) * 2 + 1] = clip_coord(jy);
    jvalid[b * 300 + t] = (score >= 0.008f) ? 1 : 0;
}

// Top-5000 centers (from merged cm) -> line endpoints -> nearest-junction keys.
__global__ void lines_kernel(const u64* __restrict__ cmk,
                             const float* __restrict__ junc,
                             const int* __restrict__ jvalid,
                             const float* __restrict__ out,
                             int* __restrict__ lkeys) {
    const int b = blockIdx.y;
    const int t = blockIdx.x * 256 + threadIdx.x;

    __shared__ float jx[300], jy[300];
    __shared__ int jv[300];
    for (int i = threadIdx.x; i < 300; i += 256) {
        jx[i] = junc[(size_t)(b * 300 + i) * 2];
        jy[i] = junc[(size_t)(b * 300 + i) * 2 + 1];
        jv[i] = jvalid[b * 300 + i];
    }
    __syncthreads();

    if (t >= 8192) return;
    if (t >= 5000) { lkeys[b * 8192 + t] = 0x7FFFFFFF; return; }

    u64 key = cmk[(size_t)b * 5000 + t];
    unsigned idx = 0xFFFFFFFFu - (unsigned)(key & 0xFFFFFFFFull);
    const float* c0 = out + OFF_COFF + (size_t)(b * 2) * HWSZ;
    const float* c1 = c0 + HWSZ;
    const float* lv = out + OFF_LVEC + (size_t)(b * 4) * HWSZ;

    float cx = (float)(idx % IMG) + c0[idx] + 0.5f;
    float cy = (float)(idx / IMG) + c1[idx] + 0.5f;
    float e0x = clip_coord(cx + lv[idx]);
    float e0y = clip_coord(cy + lv[HWSZ + idx]);
    float e1x = clip_coord(cx + lv[2 * HWSZ + idx]);
    float e1y = clip_coord(cy + lv[3 * HWSZ + idx]);

    float m1 = 1e18f, m2 = 1e18f;
    int i1 = 0, i2 = 0;
    for (int j = 0; j < 300; ++j) {
        if (jv[j]) {
            float dx = e0x - jx[j], dy = e0y - jy[j];
            float d = dx * dx + dy * dy;
            if (d < m1) { m1 = d; i1 = j; }
            dx = e1x - jx[j]; dy = e1y - jy[j];
            d = dx * dx + dy * dy;
            if (d < m2) { m2 = d; i2 = j; }
        }
    }
    int imin = min(i1, i2), imax = max(i1, i2);
    lkeys[b * 8192 + t] = (i1 != i2) ? (imin * 300 + imax) : BIGK;
}

// Dedup sorted keys -> line segments + mask.
__global__ void finalize_kernel(const int* __restrict__ lkeys,
                                const float* __restrict__ junc,
                                float* __restrict__ out) {
    const int b = blockIdx.y;
    const int t = blockIdx.x * 256 + threadIdx.x;
    if (t >= 5000) return;
    const int* lk = lkeys + b * 8192;
    int sk = lk[t];
    bool first = ((t == 0) || (sk != lk[t - 1])) && (sk < BIGK);
    int a  = first ? sk / 300 : 0;
    int bb = first ? sk % 300 : 0;
    float p0x = junc[(size_t)(b * 300 + a) * 2];
    float p0y = junc[(size_t)(b * 300 + a) * 2 + 1];
    float p1x = junc[(size_t)(b * 300 + bb) * 2];
    float p1y = junc[(size_t)(b * 300 + bb) * 2 + 1];
    if (p0y > p1y) {
        float tx = p0x; p0x = p1x; p1x = tx;
        float ty = p0y; p0y = p1y; p1y = ty;
    }
    size_t base = OFF_LOI + (size_t)(b * 5000 + t) * 4;
    out[base]     = p0x;
    out[base + 1] = p0y;
    out[base + 2] = p1x;
    out[base + 3] = p1y;
    out[OFF_MASK + b * 5000 + t] = first ? 1.0f : 0.0f;
}

extern "C" void kernel_launch(void* const* d_in, const int* in_sizes, int n_in,
                              void* d_out, int out_size, void* d_ws, size_t ws_size,
                              hipStream_t stream) {
    const float* feat  = (const float*)d_in[0];
    const float* w1    = (const float*)d_in[1];
    const float* b1    = (const float*)d_in[2];
    const float* gamma = (const float*)d_in[3];
    const float* beta  = (const float*)d_in[4];
    const float* mean  = (const float*)d_in[5];
    const float* var   = (const float*)d_in[6];
    const float* w2    = (const float*)d_in[7];
    const float* b2    = (const float*)d_in[8];
    float* out = (float*)d_out;
    char*  ws  = (char*)d_ws;

    if (ws_size < WS_NEED_MIN) return;

    float* y1 = (float*)(ws + WS_Y1);
    u64* jsort = (u64*)(ws + WS_JSORT);
    float* junc = (float*)(ws + WS_JUNC);
    int* jvalid = (int*)(ws + WS_JVAL);
    int* lkeys  = (int*)(ws + WS_LKEY);
    u64* csort = (u64*)(ws + WS_CSORT);
    short* wpk = (short*)(ws + WS_WPK);
    float* bns = (float*)(ws + WS_BNS);
    u64* jm    = (u64*)(ws + WS_JM);
    u64* cm    = (u64*)(ws + WS_CM);
    short* fpk = (short*)(ws + WS_FPK);

    if (ws_size >= WS_NEED_PK) {
        // 0. pack conv1 weights (+ BN scale in last block) -> wpk, bns
        wpack_pk_kernel<<<dim3(6913), dim3(256), 0, stream>>>(w1, wpk, gamma, var, bns);
        // 0b. pack feat into split-bf16 zero-bordered swizzled image -> fpk
        pack_feat_kernel<<<dim3(13122), dim3(256), 0, stream>>>(feat, fpk);
        // 1. conv1 + BN + ReLU via reg-prefetch pipelined MFMA
        conv1_mfma_pk<<<dim3(4800), dim3(256), 0, stream>>>(
            fpk, wpk, b1, bns, beta, mean, y1);
    } else {
        // fallback: legacy path (workspace too small for fpk)
        wpack_kernel<<<dim3(6912), dim3(256), 0, stream>>>(w1, wpk);
        conv1_mfma<<<dim3(4800), dim3(256), 0, stream>>>(
            feat, wpk, b1, gamma, beta, mean, var, y1);
    }

    // 2. conv2 (grouped, SEL channels only) -> maps in d_out
    conv2_kernel<<<dim3(5, 10, NB * 6), dim3(16, 16), 0, stream>>>(y1, w2, b2, out);

    // 3. NMS + pack sort keys
    nms_pack_kernel<<<dim3(NB * 100), dim3(256), 0, stream>>>(out, jsort, csort);

    // 4. sort each 8192-chunk descending (8 arrays x 4 chunks)
    sort64_ldsA<<<dim3(32), dim3(1024), 0, stream>>>(jsort);

    // 5. exact top-300 / top-5000 by rank-merge of sorted chunks
    merge_topk_kernel<<<dim3(83, NB), dim3(256), 0, stream>>>(jsort, csort, jm, cm);

    // 6. junctions
    junction_kernel<<<dim3(NB), dim3(320), 0, stream>>>(jm, out, junc, jvalid);

    // 7. line keys
    lines_kernel<<<dim3(32, NB), dim3(256), 0, stream>>>(cm, junc, jvalid, out, lkeys);

    // 8. sort line keys ascending (full LDS)
    sort32_lds<<<dim3(NB), dim3(1024), 0, stream>>>(lkeys);

    // 9. dedup + emit loi/mask
    finalize_kernel<<<dim3(20, NB), dim3(256), 0, stream>>>(lkeys, junc, out);
}